// Round 7
// baseline (439.046 us; speedup 1.0000x reference)
//
#include <hip/hip_runtime.h>
#include <hip/hip_bf16.h>
#include <stdint.h>

typedef __bf16 bf16;
typedef __attribute__((ext_vector_type(4))) __bf16 bf16x4;
typedef __attribute__((ext_vector_type(8))) __bf16 bf16x8;
typedef __attribute__((ext_vector_type(4))) float f32x4;

#define MFMA16(a, b, c) __builtin_amdgcn_mfma_f32_16x16x32_bf16((a), (b), (c), 0, 0, 0)

// scale (1/sqrt(32)) * log2(e), folded into q at the gemm1 epilogue
#define QSC (0.17677669529663687f * 1.4426950408889634f)

__device__ __forceinline__ void async_cp16(const bf16* g, bf16* l) {
  __builtin_amdgcn_global_load_lds(
      (const __attribute__((address_space(1))) void*)g,
      (__attribute__((address_space(3))) void*)l, 16, 0, 0);
}

// ---------- fp32 -> bf16 elementwise cast (x), vectorized ----------
__global__ __launch_bounds__(256) void convx_k(const float* __restrict__ in,
                                               bf16* __restrict__ out, int n) {
  int i = (blockIdx.x * 256 + threadIdx.x) * 4;
  const int stride = gridDim.x * 256 * 4;
  for (; i < n; i += stride) {
    const f32x4 f = *(const f32x4*)(in + i);
    bf16x4 o;
    o[0] = (bf16)f[0]; o[1] = (bf16)f[1]; o[2] = (bf16)f[2]; o[3] = (bf16)f[3];
    *(bf16x4*)(out + i) = o;
  }
}

// ---------- transpose fp32 (R x C) -> bf16 (C x R), 64x64 tiles ----------
__global__ __launch_bounds__(256) void transpose_k(const float* __restrict__ in,
                                                   bf16* __restrict__ out, int R, int C) {
  __shared__ bf16 t[64][65];
  const int bc = blockIdx.x * 64;
  const int br = blockIdx.y * 64;
  const int tx = threadIdx.x & 63, ty = threadIdx.x >> 6;
#pragma unroll
  for (int r = ty; r < 64; r += 4) t[r][tx] = (bf16)in[(br + r) * C + bc + tx];
  __syncthreads();
#pragma unroll
  for (int r = ty; r < 64; r += 4) out[(bc + r) * R + br + tx] = t[tx][r];
}

// ---------------- BMx128 bf16 GEMM, BK=32, BT is N-major (N x K) ----------------
// MODE 0: fp32 store to C. MODE 1: qkv epilogue with RoPE + scatter (bf16).
template <int MODE, int BM>
__global__ __launch_bounds__(256) void gemm128(
    const bf16* __restrict__ A, const bf16* __restrict__ BT, int M, int N, int K,
    float* __restrict__ C, bf16* __restrict__ qws, bf16* __restrict__ kws,
    bf16* __restrict__ vT, const float* __restrict__ ropeC, const float* __restrict__ ropeS) {
  constexpr int MT = BM / 32;  // 16-row tiles per wave
  __shared__ __align__(16) bf16 As[BM * 32];
  __shared__ __align__(16) bf16 Bs[128 * 32];
  const int tid = threadIdx.x;
  const int lane = tid & 63, wave = tid >> 6;
  const int l16 = lane & 15, quad = lane >> 4;
  const int wm = (wave >> 1) * (BM / 2), wn = (wave & 1) * 64;
  const int bm = blockIdx.y, bn = blockIdx.x;

  const bf16* ag = A + (bm * BM + (tid >> 2)) * K + (tid & 3) * 8;
  const bf16* bg = BT + (bn * 128 + (tid >> 2)) * K + (tid & 3) * 8;
  bf16* la = &As[tid * 8];
  bf16* lb = &Bs[tid * 8];

  f32x4 acc[MT][4] = {};

  for (int k0 = 0; k0 < K; k0 += 32) {
    async_cp16(ag + k0, la);
    if (BM == 128) async_cp16(ag + 64 * K + k0, la + 2048);
    async_cp16(bg + k0, lb);
    async_cp16(bg + 64 * K + k0, lb + 2048);
    __syncthreads();
    bf16x8 af[MT], bff[4];
#pragma unroll
    for (int t = 0; t < MT; ++t)
      af[t] = *(const bf16x8*)&As[(wm + t * 16 + l16) * 32 + quad * 8];
#pragma unroll
    for (int t = 0; t < 4; ++t)
      bff[t] = *(const bf16x8*)&Bs[(wn + t * 16 + l16) * 32 + quad * 8];
#pragma unroll
    for (int mt = 0; mt < MT; ++mt)
#pragma unroll
      for (int nt = 0; nt < 4; ++nt) acc[mt][nt] = MFMA16(af[mt], bff[nt], acc[mt][nt]);
    __syncthreads();
  }

  if (MODE == 0) {
#pragma unroll
    for (int mt = 0; mt < MT; ++mt)
#pragma unroll
      for (int i = 0; i < 4; ++i) {
        const int row = bm * BM + wm + mt * 16 + quad * 4 + i;
#pragma unroll
        for (int nt = 0; nt < 4; ++nt) {
          const int col = bn * 128 + wn + nt * 16 + l16;
          C[row * N + col] = acc[mt][nt][i];
        }
      }
  } else {
    // per-wave LDS bounce buffer (reuses Bs; safe after final barrier above)
    bf16* tb = &Bs[wave * 512];  // 16 x 16 tile, stride 20 (conflict-free)
#pragma unroll
    for (int mt = 0; mt < MT; ++mt) {
      const int s0 = bm * BM + wm + mt * 16;  // = b*2048 + sbase, 16-aligned
      const int b = s0 >> 11, sbase = s0 & 2047;
#pragma unroll
      for (int nt = 0; nt < 4; ++nt) {
        const int colb = bn * 128 + wn + nt * 16;
        const int sec = colb >> 10, rem = colb & 1023;
        const int h = rem >> 6, d0 = rem & 63;
        if (sec < 2) {  // q or k: RoPE, bounce through LDS for b64 stores
          const int d = d0 + l16;
#pragma unroll
          for (int i = 0; i < 4; ++i) {
            const int s = sbase + quad * 4 + i;
            float v = acc[mt][nt][i];
            float pr = __shfl_xor(v, 1);  // partner dim d^1 (lane l16^1)
            float rot = (d & 1) ? pr : -pr;
            float rv = v * ropeC[s * 64 + d] + rot * ropeS[s * 64 + d];
            if (sec == 0) rv *= QSC;  // fold softmax scale*log2e into q
            tb[(quad * 4 + i) * 20 + l16] = (bf16)rv;
          }
          bf16* dst = ((sec == 0) ? qws : kws) + ((b * 16 + h) * 2048 + sbase) * 64 + d0;
          bf16x4 seg = *(const bf16x4*)&tb[l16 * 20 + quad * 4];
          *(bf16x4*)(dst + l16 * 64 + quad * 4) = seg;
        } else {  // v: pack 4 consecutive s at fixed d, store b64 to vT (d-major)
          const int d = d0 + l16;
          bf16x4 pk;
#pragma unroll
          for (int i = 0; i < 4; ++i) pk[i] = (bf16)acc[mt][nt][i];
          *(bf16x4*)(vT + ((b * 16 + h) * 64 + d) * 2048 + sbase + quad * 4) = pk;
        }
      }
    }
  }
}

// ---------------- dual-triangle attention v4: LDS-free ----------------
// grid: 1024 blocks = 32 (b,h) * 32 row-blocks(64 rows); wave owns 16 Q-rows x
// full K (64 jt of 32 cols). S computed as S^T (A=K, B=Q): lane(l16,q) reg r =
// score[Qrow=rowbase+l16][j=j0+nt*16+q*4+r]. PV uses the SAME k-permutation
// pi(q,i)=nt*16+q*4+(i&3) on P (lane-local exps, NO shuffle/LDS) and on V
// (two bf16x4 loads per B-frag). Triangle split: [pure-down | 1 mixed | pure-up],
// pure tiles load+compute one K-half. K-frags prefetched one jt ahead.
__global__ __launch_bounds__(256) void attn_k(const bf16* __restrict__ qws,
                                              const bf16* __restrict__ kws,
                                              const bf16* __restrict__ vT,
                                              bf16* __restrict__ aw) {
  const int tid = threadIdx.x;
  const int lane = tid & 63, wave = tid >> 6;
  const int l16 = lane & 15, quad = lane >> 4;
  const int bh = blockIdx.x >> 5, rbl = blockIdx.x & 31;
  const int b = bh >> 4, h = bh & 15;
  const int rowbase = rbl * 64 + wave * 16;

  const bf16* qb = qws + (bh * 2048 + rowbase) * 64;
  const bf16* kb = kws + bh * 2048 * 64;
  const bf16* vb = vT + bh * 64 * 2048;

  bf16x8 qf0 = *(const bf16x8*)(qb + l16 * 64 + quad * 8);        // up half (q pre-scaled)
  bf16x8 qf1 = *(const bf16x8*)(qb + l16 * 64 + 32 + quad * 8);   // down half

  f32x4 o[4] = {};
  float lp = 0.f;
  const f32x4 zz = {};
  union V8 { bf16x8 v8; bf16x4 v4[2]; };

  // K-frag loads: half hf (0=up cols 0-31, 1=down cols 32-63), tile jtv, nt in {0,1}
#define KLOAD(dst, jtv, hf)                                                          \
  {                                                                                  \
    dst[0] = *(const bf16x8*)(kb + ((jtv) * 32 + l16) * 64 + (hf) * 32 + quad * 8);  \
    dst[1] = *(const bf16x8*)(kb + ((jtv) * 32 + 16 + l16) * 64 + (hf) * 32 + quad * 8); \
  }

#define JT_BODY(TM, jt)                                                              \
  {                                                                                  \
    const int j0 = (jt) * 32;                                                        \
    V8 vfr[4];                                                                       \
    _Pragma("unroll") for (int ntd = 0; ntd < 4; ++ntd) {                            \
      const bf16* vp = vb + (ntd * 16 + l16) * 2048 + j0 + quad * 4;                 \
      vfr[ntd].v4[0] = *(const bf16x4*)vp;                                           \
      vfr[ntd].v4[1] = *(const bf16x4*)(vp + 16);                                    \
    }                                                                                \
    f32x4 sU[2], sD[2];                                                              \
    _Pragma("unroll") for (int nt = 0; nt < 2; ++nt) {                               \
      if (TM != 0) sU[nt] = MFMA16(kcu[nt], qf0, zz);                                \
      if (TM != 2) sD[nt] = MFMA16(kcd[nt], qf1, zz);                                \
    }                                                                                \
    bf16x8 af;                                                                       \
    float ls = 0.f;                                                                  \
    _Pragma("unroll") for (int nt = 0; nt < 2; ++nt)                                 \
      _Pragma("unroll") for (int r = 0; r < 4; ++r) {                                \
        float x;                                                                     \
        if (TM == 0) x = sD[nt][r];                                                  \
        else if (TM == 2) x = sU[nt][r];                                             \
        else {                                                                       \
          const int jcol = j0 + nt * 16 + quad * 4 + r;                              \
          x = (jcol <= rowbase + l16) ? sD[nt][r] : sU[nt][r];                       \
        }                                                                            \
        float pe = exp2f(x);                                                         \
        ls += pe;                                                                    \
        af[nt * 4 + r] = (bf16)pe;                                                   \
      }                                                                              \
    lp += ls;                                                                        \
    _Pragma("unroll") for (int ntd = 0; ntd < 4; ++ntd)                              \
        o[ntd] = MFMA16(af, vfr[ntd].v8, o[ntd]);                                    \
  }

  bf16x8 kcu[2], kcd[2], knu[2], knd[2];
  const int td = rowbase >> 5;  // jt<td pure-down, jt==td mixed, jt>td pure-up

  if (td > 0) {
    KLOAD(kcd, 0, 1);
    for (int jt = 0; jt < td; ++jt) {
      const int jn = (jt + 1 < td) ? jt + 1 : jt;
      KLOAD(knd, jn, 1);
      JT_BODY(0, jt)
      kcd[0] = knd[0]; kcd[1] = knd[1];
    }
  }
  {  // mixed tile (always exactly one)
    KLOAD(kcd, td, 1);
    KLOAD(kcu, td, 0);
    JT_BODY(1, td)
  }
  if (td + 1 < 64) {
    KLOAD(kcu, td + 1, 0);
    for (int jt = td + 1; jt < 64; ++jt) {
      const int jn = (jt + 1 < 64) ? jt + 1 : jt;
      KLOAD(knu, jn, 0);
      JT_BODY(2, jt)
      kcu[0] = knu[0]; kcu[1] = knu[1];
    }
  }
#undef JT_BODY
#undef KLOAD

  // row-sum of l across quads (same l16 column = same Q-row)
  lp += __shfl_xor(lp, 16);
  lp += __shfl_xor(lp, 32);
  float ir[4];
#pragma unroll
  for (int r = 0; r < 4; ++r) ir[r] = 1.0f / __shfl(lp, quad * 4 + r);
  // o: lane(l16,q) reg r = O[Qrow=rowbase+q*4+r][d=ntd*16+l16]
#pragma unroll
  for (int ntd = 0; ntd < 4; ++ntd)
#pragma unroll
    for (int r = 0; r < 4; ++r)
      aw[(b * 2048 + rowbase + quad * 4 + r) * 1024 + h * 64 + ntd * 16 + l16] =
          (bf16)(o[ntd][r] * ir[r]);
}

extern "C" void kernel_launch(void* const* d_in, const int* in_sizes, int n_in,
                              void* d_out, int out_size, void* d_ws, size_t ws_size,
                              hipStream_t stream) {
  const float* x = (const float*)d_in[0];       // (2,2048,1024) fp32
  const float* w_qkv = (const float*)d_in[1];   // (1024,3072) fp32
  const float* w_proj = (const float*)d_in[2];  // (1024,1024) fp32
  const float* ropeC = (const float*)d_in[3];   // (2048,64) fp32
  const float* ropeS = (const float*)d_in[4];   // (2048,64) fp32
  float* out = (float*)d_out;                   // (2,2048,1024) fp32

  char* ws = (char*)d_ws;
  bf16* xb = (bf16*)ws;     ws += (size_t)4194304 * 2;  // (4096,1024) bf16
  bf16* wqkvT = (bf16*)ws;  ws += (size_t)3145728 * 2;  // (3072,1024) N-major bf16
  bf16* wprojT = (bf16*)ws; ws += (size_t)1048576 * 2;  // (1024,1024) N-major bf16
  bf16* qws = (bf16*)ws;    ws += (size_t)4194304 * 2;  // (2,16,2048,64), q pre-scaled
  bf16* kws = (bf16*)ws;    ws += (size_t)4194304 * 2;  // (2,16,2048,64)
  bf16* vT = (bf16*)ws;     ws += (size_t)4194304 * 2;  // (2,16,64,2048)
  bf16* aw = (bf16*)ws;     ws += (size_t)4194304 * 2;  // (4096,1024)

  convx_k<<<1024, 256, 0, stream>>>(x, xb, 4194304);
  transpose_k<<<dim3(3072 / 64, 1024 / 64), 256, 0, stream>>>(w_qkv, wqkvT, 1024, 3072);
  transpose_k<<<dim3(1024 / 64, 1024 / 64), 256, 0, stream>>>(w_proj, wprojT, 1024, 1024);

  gemm128<1, 128><<<dim3(3072 / 128, 4096 / 128), 256, 0, stream>>>(
      xb, wqkvT, 4096, 3072, 1024, nullptr, qws, kws, vT, ropeC, ropeS);
  attn_k<<<1024, 256, 0, stream>>>(qws, kws, vT, aw);
  gemm128<0, 64><<<dim3(1024 / 128, 4096 / 64), 256, 0, stream>>>(
      aw, wprojT, 4096, 1024, 1024, out, nullptr, nullptr, nullptr, nullptr, nullptr);
}

// Round 8
// 217.097 us; speedup vs baseline: 2.0223x; 2.0223x over previous
//
#include <hip/hip_runtime.h>
#include <hip/hip_bf16.h>
#include <stdint.h>

typedef __bf16 bf16;
typedef __attribute__((ext_vector_type(4))) __bf16 bf16x4;
typedef __attribute__((ext_vector_type(8))) __bf16 bf16x8;
typedef __attribute__((ext_vector_type(4))) float f32x4;

#define MFMA16(a, b, c) __builtin_amdgcn_mfma_f32_16x16x32_bf16((a), (b), (c), 0, 0, 0)

// scale (1/sqrt(32)) * log2(e), folded into q at the gemm1 epilogue
#define QSC (0.17677669529663687f * 1.4426950408889634f)

__device__ __forceinline__ void async_cp16(const bf16* g, bf16* l) {
  __builtin_amdgcn_global_load_lds(
      (const __attribute__((address_space(1))) void*)g,
      (__attribute__((address_space(3))) void*)l, 16, 0, 0);
}

// ---------- fp32 -> bf16 elementwise cast (x), vectorized ----------
__global__ __launch_bounds__(256) void convx_k(const float* __restrict__ in,
                                               bf16* __restrict__ out, int n) {
  int i = (blockIdx.x * 256 + threadIdx.x) * 4;
  const int stride = gridDim.x * 256 * 4;
  for (; i < n; i += stride) {
    const f32x4 f = *(const f32x4*)(in + i);
    bf16x4 o;
    o[0] = (bf16)f[0]; o[1] = (bf16)f[1]; o[2] = (bf16)f[2]; o[3] = (bf16)f[3];
    *(bf16x4*)(out + i) = o;
  }
}

// ---------- transpose fp32 (R x C) -> bf16 (C x R), 64x64 tiles ----------
__global__ __launch_bounds__(256) void transpose_k(const float* __restrict__ in,
                                                   bf16* __restrict__ out, int R, int C) {
  __shared__ bf16 t[64][65];
  const int bc = blockIdx.x * 64;
  const int br = blockIdx.y * 64;
  const int tx = threadIdx.x & 63, ty = threadIdx.x >> 6;
#pragma unroll
  for (int r = ty; r < 64; r += 4) t[r][tx] = (bf16)in[(br + r) * C + bc + tx];
  __syncthreads();
#pragma unroll
  for (int r = ty; r < 64; r += 4) out[(bc + r) * R + br + tx] = t[tx][r];
}

// ---------------- BMx128 bf16 GEMM, BK=32, BT is N-major (N x K) ----------------
// MODE 0: fp32 store to C. MODE 1: qkv epilogue with RoPE + scatter (bf16).
// vT is stored with the attention pi-permutation applied to s within each
// 64-block: pos(s) = (s&~63) | (ks*32 + quad*8 + sub*4 + r) for
// s&63 = ks*32 + sub*16 + quad*4 + r. This makes attention V B-frags single
// contiguous b128 reads matching the register-P A-frag k-slot order.
template <int MODE, int BM>
__global__ __launch_bounds__(256) void gemm128(
    const bf16* __restrict__ A, const bf16* __restrict__ BT, int M, int N, int K,
    float* __restrict__ C, bf16* __restrict__ qws, bf16* __restrict__ kws,
    bf16* __restrict__ vT, const float* __restrict__ ropeC, const float* __restrict__ ropeS) {
  constexpr int MT = BM / 32;  // 16-row tiles per wave
  __shared__ __align__(16) bf16 As[BM * 32];
  __shared__ __align__(16) bf16 Bs[128 * 32];
  const int tid = threadIdx.x;
  const int lane = tid & 63, wave = tid >> 6;
  const int l16 = lane & 15, quad = lane >> 4;
  const int wm = (wave >> 1) * (BM / 2), wn = (wave & 1) * 64;
  const int bm = blockIdx.y, bn = blockIdx.x;

  const bf16* ag = A + (bm * BM + (tid >> 2)) * K + (tid & 3) * 8;
  const bf16* bg = BT + (bn * 128 + (tid >> 2)) * K + (tid & 3) * 8;
  bf16* la = &As[tid * 8];
  bf16* lb = &Bs[tid * 8];

  f32x4 acc[MT][4] = {};

  for (int k0 = 0; k0 < K; k0 += 32) {
    async_cp16(ag + k0, la);
    if (BM == 128) async_cp16(ag + 64 * K + k0, la + 2048);
    async_cp16(bg + k0, lb);
    async_cp16(bg + 64 * K + k0, lb + 2048);
    __syncthreads();
    bf16x8 af[MT], bff[4];
#pragma unroll
    for (int t = 0; t < MT; ++t)
      af[t] = *(const bf16x8*)&As[(wm + t * 16 + l16) * 32 + quad * 8];
#pragma unroll
    for (int t = 0; t < 4; ++t)
      bff[t] = *(const bf16x8*)&Bs[(wn + t * 16 + l16) * 32 + quad * 8];
#pragma unroll
    for (int mt = 0; mt < MT; ++mt)
#pragma unroll
      for (int nt = 0; nt < 4; ++nt) acc[mt][nt] = MFMA16(af[mt], bff[nt], acc[mt][nt]);
    __syncthreads();
  }

  if (MODE == 0) {
#pragma unroll
    for (int mt = 0; mt < MT; ++mt)
#pragma unroll
      for (int i = 0; i < 4; ++i) {
        const int row = bm * BM + wm + mt * 16 + quad * 4 + i;
#pragma unroll
        for (int nt = 0; nt < 4; ++nt) {
          const int col = bn * 128 + wn + nt * 16 + l16;
          C[row * N + col] = acc[mt][nt][i];
        }
      }
  } else {
    // per-wave LDS bounce buffer (reuses Bs; safe after final barrier above)
    bf16* tb = &Bs[wave * 512];  // 16 x 16 tile, stride 20 (conflict-free)
#pragma unroll
    for (int mt = 0; mt < MT; ++mt) {
      const int s0 = bm * BM + wm + mt * 16;  // = b*2048 + sbase, 16-aligned
      const int b = s0 >> 11, sbase = s0 & 2047;
#pragma unroll
      for (int nt = 0; nt < 4; ++nt) {
        const int colb = bn * 128 + wn + nt * 16;
        const int sec = colb >> 10, rem = colb & 1023;
        const int h = rem >> 6, d0 = rem & 63;
        if (sec < 2) {  // q or k: RoPE, bounce through LDS for b64 stores
          const int d = d0 + l16;
#pragma unroll
          for (int i = 0; i < 4; ++i) {
            const int s = sbase + quad * 4 + i;
            float v = acc[mt][nt][i];
            float pr = __shfl_xor(v, 1);  // partner dim d^1 (lane l16^1)
            float rot = (d & 1) ? pr : -pr;
            float rv = v * ropeC[s * 64 + d] + rot * ropeS[s * 64 + d];
            if (sec == 0) rv *= QSC;  // fold softmax scale*log2e into q
            tb[(quad * 4 + i) * 20 + l16] = (bf16)rv;
          }
          bf16* dst = ((sec == 0) ? qws : kws) + ((b * 16 + h) * 2048 + sbase) * 64 + d0;
          bf16x4 seg = *(const bf16x4*)&tb[l16 * 20 + quad * 4];
          *(bf16x4*)(dst + l16 * 64 + quad * 4) = seg;
        } else {  // v: store b64 to vT (d-major) at pi-permuted s position
          const int d = d0 + l16;
          const int s4 = sbase + quad * 4;
          const int a = (s4 >> 4) & 3;
          const int p = (s4 & ~63) | ((a >> 1) * 32 + quad * 8 + (a & 1) * 4);
          bf16x4 pk;
#pragma unroll
          for (int i = 0; i < 4; ++i) pk[i] = (bf16)acc[mt][nt][i];
          *(bf16x4*)(vT + ((b * 16 + h) * 64 + d) * 2048 + p) = pk;
        }
      }
    }
  }
}

// ---------------- dual-triangle attention v5: cooperative LDS K/V, register P ----
// grid: 512 blocks = 32 (b,h) * 16 Q-blocks(128 rows); 4 waves own 32 rows each.
// Per jt (64 K-cols): block stages K-tile(64j x 64dh) + V-tile(64d x 64j) via
// global_load_lds w16 (chunk-rotated rows: 16B chunk c of row r at pos (c+r)&7
// -> conflict-free b128 frag reads, DMA-contiguous staging). S computed as S^T
// (A=K, B=Q): lane's 16 exps stay in registers as the PV A-frag (pi-packing);
// V was pre-permuted in gemm1 so B-frags are single b128. Triangle split per
// wave: tdw = rbase>>6; pure tiles run half the QK MFMAs, no selects.
__global__ __launch_bounds__(256) void attn_k(const bf16* __restrict__ qws,
                                              const bf16* __restrict__ kws,
                                              const bf16* __restrict__ vT,
                                              bf16* __restrict__ aw) {
  __shared__ __align__(16) bf16 Ks[64 * 64];
  __shared__ __align__(16) bf16 Vs[64 * 64];
  const int tid = threadIdx.x;
  const int lane = tid & 63, wave = tid >> 6;
  const int l16 = lane & 15, quad = lane >> 4;
  const int bh = blockIdx.x >> 4, qblk = blockIdx.x & 15;
  const int b = bh >> 4, h = bh & 15;
  const int rbase = qblk * 128 + wave * 32;

  const bf16* qb = qws + (bh * 2048 + rbase) * 64;
  const bf16* kb = kws + bh * 2048 * 64;
  const bf16* vb = vT + bh * 64 * 2048;

  // staging: wave stages rows [wave*16, +16) of both tiles; 2 insts each.
  const int r0 = wave * 16 + (lane >> 3);
  const int c0 = ((lane & 7) - r0) & 7;  // chunk rotation (r0 and r0+8 give same c)
  const bf16* kst0 = kb + r0 * 64 + c0 * 8;
  const bf16* kst1 = kb + (r0 + 8) * 64 + c0 * 8;
  const bf16* vst0 = vb + r0 * 2048 + c0 * 8;
  const bf16* vst1 = vb + (r0 + 8) * 2048 + c0 * 8;
  bf16* kd0 = Ks + wave * 1024;
  bf16* kd1 = Ks + wave * 1024 + 512;
  bf16* vd0 = Vs + wave * 1024;
  bf16* vd1 = Vs + wave * 1024 + 512;

  bf16x8 qf[2][2];
#pragma unroll
  for (int g = 0; g < 2; ++g)
#pragma unroll
    for (int hf = 0; hf < 2; ++hf)
      qf[g][hf] = *(const bf16x8*)(qb + (g * 16 + l16) * 64 + hf * 32 + quad * 8);

  f32x4 o[2][4] = {};
  float lp[2] = {0.f, 0.f};
  const f32x4 zz = {};
  const int tdw = rbase >> 6;  // jt<tdw pure-down, ==tdw mixed, >tdw pure-up

#define ATTN_BODY(TM)                                                                 \
  {                                                                                   \
    _Pragma("unroll") for (int ks = 0; ks < 2; ++ks) {                                \
      bf16x8 vf[4];                                                                   \
      _Pragma("unroll") for (int ntd = 0; ntd < 4; ++ntd)                             \
        vf[ntd] = *(const bf16x8*)(Vs + (ntd * 16 + l16) * 64 +                       \
                                   ((ks * 4 + quad + l16) & 7) * 8);                  \
      bf16x8 kfU[2], kfD[2];                                                          \
      _Pragma("unroll") for (int s = 0; s < 2; ++s) {                                 \
        const int ro = ((ks * 2 + s) * 16 + l16) * 64;                                \
        if (TM != 0) kfU[s] = *(const bf16x8*)(Ks + ro + ((quad + l16) & 7) * 8);     \
        if (TM != 2) kfD[s] = *(const bf16x8*)(Ks + ro + ((4 + quad + l16) & 7) * 8); \
      }                                                                               \
      f32x4 sU[2][2], sD[2][2];                                                       \
      _Pragma("unroll") for (int s = 0; s < 2; ++s)                                   \
        _Pragma("unroll") for (int g = 0; g < 2; ++g) {                               \
          if (TM != 0) sU[s][g] = MFMA16(kfU[s], qf[g][0], zz);                       \
          if (TM != 2) sD[s][g] = MFMA16(kfD[s], qf[g][1], zz);                       \
        }                                                                             \
      _Pragma("unroll") for (int g = 0; g < 2; ++g) {                                 \
        bf16x8 af;                                                                    \
        float ls = 0.f;                                                               \
        _Pragma("unroll") for (int s = 0; s < 2; ++s)                                 \
          _Pragma("unroll") for (int r = 0; r < 4; ++r) {                             \
            float x;                                                                  \
            if (TM == 0) x = sD[s][g][r];                                             \
            else if (TM == 2) x = sU[s][g][r];                                        \
            else {                                                                    \
              const int jcol = jt * 64 + (ks * 2 + s) * 16 + quad * 4 + r;            \
              x = (jcol <= rbase + g * 16 + l16) ? sD[s][g][r] : sU[s][g][r];         \
            }                                                                         \
            float pe = exp2f(x);                                                      \
            ls += pe;                                                                 \
            af[s * 4 + r] = (bf16)pe;                                                 \
          }                                                                           \
        lp[g] += ls;                                                                  \
        _Pragma("unroll") for (int ntd = 0; ntd < 4; ++ntd)                           \
            o[g][ntd] = MFMA16(af, vf[ntd], o[g][ntd]);                               \
      }                                                                               \
    }                                                                                 \
  }

  for (int jt = 0; jt < 32; ++jt) {
    async_cp16(kst0 + jt * 4096, kd0);
    async_cp16(kst1 + jt * 4096, kd1);
    async_cp16(vst0 + jt * 64, vd0);
    async_cp16(vst1 + jt * 64, vd1);
    __syncthreads();  // staging of tile jt visible (barrier drains vmcnt)
    if (jt < tdw) ATTN_BODY(0)
    else if (jt == tdw) ATTN_BODY(1)
    else ATTN_BODY(2)
    __syncthreads();  // all waves done reading before next overwrite
  }
#undef ATTN_BODY

  // per-row l: 4 quads hold disjoint j-partials of the same row (col = l16)
#pragma unroll
  for (int g = 0; g < 2; ++g) {
    lp[g] += __shfl_xor(lp[g], 16);
    lp[g] += __shfl_xor(lp[g], 32);
  }
#pragma unroll
  for (int g = 0; g < 2; ++g) {
    float ir[4];
#pragma unroll
    for (int r = 0; r < 4; ++r) ir[r] = 1.0f / __shfl(lp[g], quad * 4 + r);
#pragma unroll
    for (int ntd = 0; ntd < 4; ++ntd)
#pragma unroll
      for (int r = 0; r < 4; ++r)
        aw[(b * 2048 + rbase + g * 16 + quad * 4 + r) * 1024 + h * 64 + ntd * 16 + l16] =
            (bf16)(o[g][ntd][r] * ir[r]);
  }
}

extern "C" void kernel_launch(void* const* d_in, const int* in_sizes, int n_in,
                              void* d_out, int out_size, void* d_ws, size_t ws_size,
                              hipStream_t stream) {
  const float* x = (const float*)d_in[0];       // (2,2048,1024) fp32
  const float* w_qkv = (const float*)d_in[1];   // (1024,3072) fp32
  const float* w_proj = (const float*)d_in[2];  // (1024,1024) fp32
  const float* ropeC = (const float*)d_in[3];   // (2048,64) fp32
  const float* ropeS = (const float*)d_in[4];   // (2048,64) fp32
  float* out = (float*)d_out;                   // (2,2048,1024) fp32

  char* ws = (char*)d_ws;
  bf16* xb = (bf16*)ws;     ws += (size_t)4194304 * 2;  // (4096,1024) bf16
  bf16* wqkvT = (bf16*)ws;  ws += (size_t)3145728 * 2;  // (3072,1024) N-major bf16
  bf16* wprojT = (bf16*)ws; ws += (size_t)1048576 * 2;  // (1024,1024) N-major bf16
  bf16* qws = (bf16*)ws;    ws += (size_t)4194304 * 2;  // (2,16,2048,64), q pre-scaled
  bf16* kws = (bf16*)ws;    ws += (size_t)4194304 * 2;  // (2,16,2048,64)
  bf16* vT = (bf16*)ws;     ws += (size_t)4194304 * 2;  // (2,16,64,2048), pi-permuted
  bf16* aw = (bf16*)ws;     ws += (size_t)4194304 * 2;  // (4096,1024)

  convx_k<<<1024, 256, 0, stream>>>(x, xb, 4194304);
  transpose_k<<<dim3(3072 / 64, 1024 / 64), 256, 0, stream>>>(w_qkv, wqkvT, 1024, 3072);
  transpose_k<<<dim3(1024 / 64, 1024 / 64), 256, 0, stream>>>(w_proj, wprojT, 1024, 1024);

  gemm128<1, 128><<<dim3(3072 / 128, 4096 / 128), 256, 0, stream>>>(
      xb, wqkvT, 4096, 3072, 1024, nullptr, qws, kws, vT, ropeC, ropeS);
  attn_k<<<512, 256, 0, stream>>>(qws, kws, vT, aw);
  gemm128<0, 64><<<dim3(1024 / 128, 4096 / 64), 256, 0, stream>>>(
      aw, wprojT, 4096, 1024, 1024, out, nullptr, nullptr, nullptr, nullptr, nullptr);
}

// Round 10
// 216.083 us; speedup vs baseline: 2.0318x; 1.0047x over previous
//
#include <hip/hip_runtime.h>
#include <hip/hip_bf16.h>
#include <stdint.h>

typedef __bf16 bf16;
typedef __attribute__((ext_vector_type(4))) __bf16 bf16x4;
typedef __attribute__((ext_vector_type(8))) __bf16 bf16x8;
typedef __attribute__((ext_vector_type(4))) float f32x4;

#define MFMA16(a, b, c) __builtin_amdgcn_mfma_f32_16x16x32_bf16((a), (b), (c), 0, 0, 0)

// scale (1/sqrt(32)) * log2(e), folded into q at the gemm1 epilogue
#define QSC (0.17677669529663687f * 1.4426950408889634f)

__device__ __forceinline__ void async_cp16(const bf16* g, bf16* l) {
  __builtin_amdgcn_global_load_lds(
      (const __attribute__((address_space(1))) void*)g,
      (__attribute__((address_space(3))) void*)l, 16, 0, 0);
}

// ---------- fp32 -> bf16 elementwise cast (x), vectorized ----------
__global__ __launch_bounds__(256) void convx_k(const float* __restrict__ in,
                                               bf16* __restrict__ out, int n) {
  int i = (blockIdx.x * 256 + threadIdx.x) * 4;
  const int stride = gridDim.x * 256 * 4;
  for (; i < n; i += stride) {
    const f32x4 f = *(const f32x4*)(in + i);
    bf16x4 o;
    o[0] = (bf16)f[0]; o[1] = (bf16)f[1]; o[2] = (bf16)f[2]; o[3] = (bf16)f[3];
    *(bf16x4*)(out + i) = o;
  }
}

// ---------- transpose fp32 (R x C) -> bf16 (C x R), 64x64 tiles ----------
__global__ __launch_bounds__(256) void transpose_k(const float* __restrict__ in,
                                                   bf16* __restrict__ out, int R, int C) {
  __shared__ bf16 t[64][65];
  const int bc = blockIdx.x * 64;
  const int br = blockIdx.y * 64;
  const int tx = threadIdx.x & 63, ty = threadIdx.x >> 6;
#pragma unroll
  for (int r = ty; r < 64; r += 4) t[r][tx] = (bf16)in[(br + r) * C + bc + tx];
  __syncthreads();
#pragma unroll
  for (int r = ty; r < 64; r += 4) out[(bc + r) * R + br + tx] = t[tx][r];
}

// ---------------- BMx128 bf16 GEMM, BK=32, BT is N-major (N x K) ----------------
// MODE 0: fp32 store to C. MODE 1: qkv epilogue with RoPE + scatter (bf16).
// vT is stored with the attention pi-permutation applied to s within each
// 64-block (see r8 comment) so attention V B-frags match register-P k-slots.
template <int MODE, int BM>
__global__ __launch_bounds__(256) void gemm128(
    const bf16* __restrict__ A, const bf16* __restrict__ BT, int M, int N, int K,
    float* __restrict__ C, bf16* __restrict__ qws, bf16* __restrict__ kws,
    bf16* __restrict__ vT, const float* __restrict__ ropeC, const float* __restrict__ ropeS) {
  constexpr int MT = BM / 32;  // 16-row tiles per wave
  __shared__ __align__(16) bf16 As[BM * 32];
  __shared__ __align__(16) bf16 Bs[128 * 32];
  const int tid = threadIdx.x;
  const int lane = tid & 63, wave = tid >> 6;
  const int l16 = lane & 15, quad = lane >> 4;
  const int wm = (wave >> 1) * (BM / 2), wn = (wave & 1) * 64;
  const int bm = blockIdx.y, bn = blockIdx.x;

  const bf16* ag = A + (bm * BM + (tid >> 2)) * K + (tid & 3) * 8;
  const bf16* bg = BT + (bn * 128 + (tid >> 2)) * K + (tid & 3) * 8;
  bf16* la = &As[tid * 8];
  bf16* lb = &Bs[tid * 8];

  f32x4 acc[MT][4] = {};

  for (int k0 = 0; k0 < K; k0 += 32) {
    async_cp16(ag + k0, la);
    if (BM == 128) async_cp16(ag + 64 * K + k0, la + 2048);
    async_cp16(bg + k0, lb);
    async_cp16(bg + 64 * K + k0, lb + 2048);
    __syncthreads();
    bf16x8 af[MT], bff[4];
#pragma unroll
    for (int t = 0; t < MT; ++t)
      af[t] = *(const bf16x8*)&As[(wm + t * 16 + l16) * 32 + quad * 8];
#pragma unroll
    for (int t = 0; t < 4; ++t)
      bff[t] = *(const bf16x8*)&Bs[(wn + t * 16 + l16) * 32 + quad * 8];
#pragma unroll
    for (int mt = 0; mt < MT; ++mt)
#pragma unroll
      for (int nt = 0; nt < 4; ++nt) acc[mt][nt] = MFMA16(af[mt], bff[nt], acc[mt][nt]);
    __syncthreads();
  }

  if (MODE == 0) {
#pragma unroll
    for (int mt = 0; mt < MT; ++mt)
#pragma unroll
      for (int i = 0; i < 4; ++i) {
        const int row = bm * BM + wm + mt * 16 + quad * 4 + i;
#pragma unroll
        for (int nt = 0; nt < 4; ++nt) {
          const int col = bn * 128 + wn + nt * 16 + l16;
          C[row * N + col] = acc[mt][nt][i];
        }
      }
  } else {
    // per-wave LDS bounce buffer (reuses Bs; safe after final barrier above)
    bf16* tb = &Bs[wave * 512];  // 16 x 16 tile, stride 20 (conflict-free)
#pragma unroll
    for (int mt = 0; mt < MT; ++mt) {
      const int s0 = bm * BM + wm + mt * 16;  // = b*2048 + sbase, 16-aligned
      const int b = s0 >> 11, sbase = s0 & 2047;
#pragma unroll
      for (int nt = 0; nt < 4; ++nt) {
        const int colb = bn * 128 + wn + nt * 16;
        const int sec = colb >> 10, rem = colb & 1023;
        const int h = rem >> 6, d0 = rem & 63;
        if (sec < 2) {  // q or k: RoPE, bounce through LDS for b64 stores
          const int d = d0 + l16;
#pragma unroll
          for (int i = 0; i < 4; ++i) {
            const int s = sbase + quad * 4 + i;
            float v = acc[mt][nt][i];
            float pr = __shfl_xor(v, 1);  // partner dim d^1 (lane l16^1)
            float rot = (d & 1) ? pr : -pr;
            float rv = v * ropeC[s * 64 + d] + rot * ropeS[s * 64 + d];
            if (sec == 0) rv *= QSC;  // fold softmax scale*log2e into q
            tb[(quad * 4 + i) * 20 + l16] = (bf16)rv;
          }
          bf16* dst = ((sec == 0) ? qws : kws) + ((b * 16 + h) * 2048 + sbase) * 64 + d0;
          bf16x4 seg = *(const bf16x4*)&tb[l16 * 20 + quad * 4];
          *(bf16x4*)(dst + l16 * 64 + quad * 4) = seg;
        } else {  // v: store b64 to vT (d-major) at pi-permuted s position
          const int d = d0 + l16;
          const int s4 = sbase + quad * 4;
          const int a = (s4 >> 4) & 3;
          const int p = (s4 & ~63) | ((a >> 1) * 32 + quad * 8 + (a & 1) * 4);
          bf16x4 pk;
#pragma unroll
          for (int i = 0; i < 4; ++i) pk[i] = (bf16)acc[mt][nt][i];
          *(bf16x4*)(vT + ((b * 16 + h) * 64 + d) * 2048 + p) = pk;
        }
      }
    }
  }
}

// ---------------- dual-triangle attention v7: dbuf + explicit vmcnt drain ----
// Identical numerics to r8 (scalar l, ocml exp2f, exact div). Structural change
// only: double-buffered K/V with ONE barrier per jt; STAGE(jt+1) issued after
// this jt's frag reads so the DMA rides under the jt math. An explicit
// s_waitcnt vmcnt(0) before each barrier guarantees cross-wave visibility of
// the LDS-DMA regardless of compiler fence modeling (suspected r9 hole).
__global__ __launch_bounds__(256) void attn_k(const bf16* __restrict__ qws,
                                              const bf16* __restrict__ kws,
                                              const bf16* __restrict__ vT,
                                              bf16* __restrict__ aw) {
  __shared__ __align__(16) bf16 Ks[2][64 * 64];
  __shared__ __align__(16) bf16 Vs[2][64 * 64];
  const int tid = threadIdx.x;
  const int lane = tid & 63, wave = tid >> 6;
  const int l16 = lane & 15, quad = lane >> 4;
  const int bh = blockIdx.x >> 4, qblk = blockIdx.x & 15;
  const int b = bh >> 4, h = bh & 15;
  const int rbase = qblk * 128 + wave * 32;

  const bf16* qb = qws + (bh * 2048 + rbase) * 64;
  const bf16* kb = kws + bh * 2048 * 64;
  const bf16* vb = vT + bh * 64 * 2048;

  // staging: wave stages rows [wave*16, +16) of both tiles; 2 insts each.
  const int r0 = wave * 16 + (lane >> 3);
  const int c0 = ((lane & 7) - r0) & 7;  // chunk rotation (r0 and r0+8 give same c)
  const bf16* kst0 = kb + r0 * 64 + c0 * 8;
  const bf16* kst1 = kb + (r0 + 8) * 64 + c0 * 8;
  const bf16* vst0 = vb + r0 * 2048 + c0 * 8;
  const bf16* vst1 = vb + (r0 + 8) * 2048 + c0 * 8;

#define STAGE(jtv)                                         \
  {                                                        \
    bf16* kdst = &Ks[(jtv) & 1][wave * 1024];              \
    bf16* vdst = &Vs[(jtv) & 1][wave * 1024];              \
    async_cp16(kst0 + (jtv) * 4096, kdst);                 \
    async_cp16(kst1 + (jtv) * 4096, kdst + 512);           \
    async_cp16(vst0 + (jtv) * 64, vdst);                   \
    async_cp16(vst1 + (jtv) * 64, vdst + 512);             \
  }

  bf16x8 qf[2][2];
#pragma unroll
  for (int g = 0; g < 2; ++g)
#pragma unroll
    for (int hf = 0; hf < 2; ++hf)
      qf[g][hf] = *(const bf16x8*)(qb + (g * 16 + l16) * 64 + hf * 32 + quad * 8);

  f32x4 o[2][4] = {};
  float lp[2] = {0.f, 0.f};
  const f32x4 zz = {};
  const int tdw = rbase >> 6;  // jt<tdw pure-down, ==tdw mixed, >tdw pure-up

#define ATTN_BODY(TM, jt)                                                             \
  {                                                                                   \
    const bf16* Kb = Ks[(jt) & 1];                                                    \
    const bf16* Vb = Vs[(jt) & 1];                                                    \
    bf16x8 vf[2][4];                                                                  \
    _Pragma("unroll") for (int ks = 0; ks < 2; ++ks)                                  \
      _Pragma("unroll") for (int ntd = 0; ntd < 4; ++ntd)                             \
        vf[ks][ntd] = *(const bf16x8*)(Vb + (ntd * 16 + l16) * 64 +                   \
                                       ((ks * 4 + quad + l16) & 7) * 8);              \
    bf16x8 kfU[2][2], kfD[2][2];                                                      \
    _Pragma("unroll") for (int ks = 0; ks < 2; ++ks)                                  \
      _Pragma("unroll") for (int s = 0; s < 2; ++s) {                                 \
        const int ro = ((ks * 2 + s) * 16 + l16) * 64;                                \
        if (TM != 0) kfU[ks][s] = *(const bf16x8*)(Kb + ro + ((quad + l16) & 7) * 8); \
        if (TM != 2)                                                                  \
          kfD[ks][s] = *(const bf16x8*)(Kb + ro + ((4 + quad + l16) & 7) * 8);        \
      }                                                                               \
    if ((jt) + 1 < 32) STAGE((jt) + 1)                                                \
    _Pragma("unroll") for (int ks = 0; ks < 2; ++ks) {                                \
      f32x4 sU[2][2], sD[2][2];                                                       \
      _Pragma("unroll") for (int s = 0; s < 2; ++s)                                   \
        _Pragma("unroll") for (int g = 0; g < 2; ++g) {                               \
          if (TM != 0) sU[s][g] = MFMA16(kfU[ks][s], qf[g][0], zz);                   \
          if (TM != 2) sD[s][g] = MFMA16(kfD[ks][s], qf[g][1], zz);                   \
        }                                                                             \
      _Pragma("unroll") for (int g = 0; g < 2; ++g) {                                 \
        bf16x8 af;                                                                    \
        float ls = 0.f;                                                               \
        _Pragma("unroll") for (int s = 0; s < 2; ++s)                                 \
          _Pragma("unroll") for (int r = 0; r < 4; ++r) {                             \
            float x;                                                                  \
            if (TM == 0) x = sD[s][g][r];                                             \
            else if (TM == 2) x = sU[s][g][r];                                        \
            else {                                                                    \
              const int jcol = (jt) * 64 + (ks * 2 + s) * 16 + quad * 4 + r;          \
              x = (jcol <= rbase + g * 16 + l16) ? sD[s][g][r] : sU[s][g][r];         \
            }                                                                         \
            float pe = exp2f(x);                                                      \
            ls += pe;                                                                 \
            af[s * 4 + r] = (bf16)pe;                                                 \
          }                                                                           \
        lp[g] += ls;                                                                  \
        _Pragma("unroll") for (int ntd = 0; ntd < 4; ++ntd)                           \
            o[g][ntd] = MFMA16(af, vf[ks][ntd], o[g][ntd]);                           \
      }                                                                               \
    }                                                                                 \
  }

  STAGE(0)
  for (int jt = 0; jt < 32; ++jt) {
    // Force each wave's pending LDS-DMA retired before the barrier: guarantees
    // cross-wave visibility of STAGE(jt) (issued one iteration ago -> free).
    asm volatile("s_waitcnt vmcnt(0)" ::: "memory");
    __syncthreads();
    if (jt < tdw) ATTN_BODY(0, jt)
    else if (jt == tdw) ATTN_BODY(1, jt)
    else ATTN_BODY(2, jt)
  }
#undef ATTN_BODY
#undef STAGE

  // per-row l: 4 quads hold disjoint j-partials of the same row (col = l16)
#pragma unroll
  for (int g = 0; g < 2; ++g) {
    lp[g] += __shfl_xor(lp[g], 16);
    lp[g] += __shfl_xor(lp[g], 32);
  }
#pragma unroll
  for (int g = 0; g < 2; ++g) {
    float ir[4];
#pragma unroll
    for (int r = 0; r < 4; ++r) ir[r] = 1.0f / __shfl(lp[g], quad * 4 + r);
#pragma unroll
    for (int ntd = 0; ntd < 4; ++ntd)
#pragma unroll
      for (int r = 0; r < 4; ++r)
        aw[(b * 2048 + rbase + g * 16 + quad * 4 + r) * 1024 + h * 64 + ntd * 16 + l16] =
            (bf16)(o[g][ntd][r] * ir[r]);
  }
}

extern "C" void kernel_launch(void* const* d_in, const int* in_sizes, int n_in,
                              void* d_out, int out_size, void* d_ws, size_t ws_size,
                              hipStream_t stream) {
  const float* x = (const float*)d_in[0];       // (2,2048,1024) fp32
  const float* w_qkv = (const float*)d_in[1];   // (1024,3072) fp32
  const float* w_proj = (const float*)d_in[2];  // (1024,1024) fp32
  const float* ropeC = (const float*)d_in[3];   // (2048,64) fp32
  const float* ropeS = (const float*)d_in[4];   // (2048,64) fp32
  float* out = (float*)d_out;                   // (2,2048,1024) fp32

  char* ws = (char*)d_ws;
  bf16* xb = (bf16*)ws;     ws += (size_t)4194304 * 2;  // (4096,1024) bf16
  bf16* wqkvT = (bf16*)ws;  ws += (size_t)3145728 * 2;  // (3072,1024) N-major bf16
  bf16* wprojT = (bf16*)ws; ws += (size_t)1048576 * 2;  // (1024,1024) N-major bf16
  bf16* qws = (bf16*)ws;    ws += (size_t)4194304 * 2;  // (2,16,2048,64), q pre-scaled
  bf16* kws = (bf16*)ws;    ws += (size_t)4194304 * 2;  // (2,16,2048,64)
  bf16* vT = (bf16*)ws;     ws += (size_t)4194304 * 2;  // (2,16,64,2048), pi-permuted
  bf16* aw = (bf16*)ws;     ws += (size_t)4194304 * 2;  // (4096,1024)

  convx_k<<<1024, 256, 0, stream>>>(x, xb, 4194304);
  transpose_k<<<dim3(3072 / 64, 1024 / 64), 256, 0, stream>>>(w_qkv, wqkvT, 1024, 3072);
  transpose_k<<<dim3(1024 / 64, 1024 / 64), 256, 0, stream>>>(w_proj, wprojT, 1024, 1024);

  gemm128<1, 128><<<dim3(3072 / 128, 4096 / 128), 256, 0, stream>>>(
      xb, wqkvT, 4096, 3072, 1024, nullptr, qws, kws, vT, ropeC, ropeS);
  attn_k<<<512, 256, 0, stream>>>(qws, kws, vT, aw);
  gemm128<0, 64><<<dim3(1024 / 128, 4096 / 64), 256, 0, stream>>>(
      aw, wprojT, 4096, 1024, 1024, out, nullptr, nullptr, nullptr, nullptr, nullptr);
}

// Round 11
// 195.994 us; speedup vs baseline: 2.2401x; 1.1025x over previous
//
#include <hip/hip_runtime.h>
#include <hip/hip_bf16.h>
#include <stdint.h>

typedef __bf16 bf16;
typedef __attribute__((ext_vector_type(4))) __bf16 bf16x4;
typedef __attribute__((ext_vector_type(8))) __bf16 bf16x8;
typedef __attribute__((ext_vector_type(4))) float f32x4;

#define MFMA16(a, b, c) __builtin_amdgcn_mfma_f32_16x16x32_bf16((a), (b), (c), 0, 0, 0)

// scale (1/sqrt(32)) * log2(e), folded into q at the gemm1 epilogue
#define QSC (0.17677669529663687f * 1.4426950408889634f)

__device__ __forceinline__ void async_cp16(const bf16* g, bf16* l) {
  __builtin_amdgcn_global_load_lds(
      (const __attribute__((address_space(1))) void*)g,
      (__attribute__((address_space(3))) void*)l, 16, 0, 0);
}

// ---------- fp32 -> bf16 elementwise cast (x), vectorized ----------
__global__ __launch_bounds__(256) void convx_k(const float* __restrict__ in,
                                               bf16* __restrict__ out, int n) {
  int i = (blockIdx.x * 256 + threadIdx.x) * 4;
  const int stride = gridDim.x * 256 * 4;
  for (; i < n; i += stride) {
    const f32x4 f = *(const f32x4*)(in + i);
    bf16x4 o;
    o[0] = (bf16)f[0]; o[1] = (bf16)f[1]; o[2] = (bf16)f[2]; o[3] = (bf16)f[3];
    *(bf16x4*)(out + i) = o;
  }
}

// ---------- transpose fp32 (R x C) -> bf16 (C x R), 64x64 tiles ----------
__global__ __launch_bounds__(256) void transpose_k(const float* __restrict__ in,
                                                   bf16* __restrict__ out, int R, int C) {
  __shared__ bf16 t[64][65];
  const int bc = blockIdx.x * 64;
  const int br = blockIdx.y * 64;
  const int tx = threadIdx.x & 63, ty = threadIdx.x >> 6;
#pragma unroll
  for (int r = ty; r < 64; r += 4) t[r][tx] = (bf16)in[(br + r) * C + bc + tx];
  __syncthreads();
#pragma unroll
  for (int r = ty; r < 64; r += 4) out[(bc + r) * R + br + tx] = t[tx][r];
}

// ---------------- BMx128 bf16 GEMM, BK=64, BT is N-major (N x K) ----------------
// LDS rows are chunk-rotated: 16B chunk c of row r sits at position (c+r)&7
// (keeps global_load_lds staging contiguous, makes b128 frag reads ~2-way only).
// MODE 0: fp32 store to C. MODE 1: qkv epilogue with RoPE + scatter (bf16);
// vT gets the attention pi-permutation on s within each 64-block (r8 comment).
template <int MODE, int BM>
__global__ __launch_bounds__(256) void gemm128(
    const bf16* __restrict__ A, const bf16* __restrict__ BT, int M, int N, int K,
    float* __restrict__ C, bf16* __restrict__ qws, bf16* __restrict__ kws,
    bf16* __restrict__ vT, const float* __restrict__ ropeC, const float* __restrict__ ropeS) {
  constexpr int MT = BM / 32;  // 16-row tiles per wave
  __shared__ __align__(16) bf16 As[BM * 64];
  __shared__ __align__(16) bf16 Bs[128 * 64];
  const int tid = threadIdx.x;
  const int lane = tid & 63, wave = tid >> 6;
  const int l16 = lane & 15, quad = lane >> 4;
  const int wm = (wave >> 1) * (BM / 2), wn = (wave & 1) * 64;
  const int bm = blockIdx.y, bn = blockIdx.x;

  // staging: thread t owns LDS row (t>>3) (+32 per inst), position t&7;
  // fetches global chunk ((t&7) - row) & 7 -> chunk g lands at pos (g+row)&7.
  const int srow = tid >> 3;
  const int schunk = ((tid & 7) - srow) & 7;
  const bf16* ag = A + (bm * BM + srow) * K + schunk * 8;
  const bf16* bg = BT + (bn * 128 + srow) * K + schunk * 8;
  bf16* la = &As[tid * 8];
  bf16* lb = &Bs[tid * 8];

  f32x4 acc[MT][4] = {};

  for (int k0 = 0; k0 < K; k0 += 64) {
    async_cp16(ag + k0, la);
    async_cp16(ag + 32 * K + k0, la + 2048);
    if (BM == 128) {
      async_cp16(ag + 64 * K + k0, la + 4096);
      async_cp16(ag + 96 * K + k0, la + 6144);
    }
    async_cp16(bg + k0, lb);
    async_cp16(bg + 32 * K + k0, lb + 2048);
    async_cp16(bg + 64 * K + k0, lb + 4096);
    async_cp16(bg + 96 * K + k0, lb + 6144);
    __syncthreads();
#pragma unroll
    for (int ks = 0; ks < 2; ++ks) {
      bf16x8 af[MT], bff[4];
#pragma unroll
      for (int t = 0; t < MT; ++t) {
        const int r = wm + t * 16 + l16;
        af[t] = *(const bf16x8*)&As[r * 64 + ((ks * 4 + quad + r) & 7) * 8];
      }
#pragma unroll
      for (int t = 0; t < 4; ++t) {
        const int r = wn + t * 16 + l16;
        bff[t] = *(const bf16x8*)&Bs[r * 64 + ((ks * 4 + quad + r) & 7) * 8];
      }
#pragma unroll
      for (int mt = 0; mt < MT; ++mt)
#pragma unroll
        for (int nt = 0; nt < 4; ++nt) acc[mt][nt] = MFMA16(af[mt], bff[nt], acc[mt][nt]);
    }
    __syncthreads();
  }

  if (MODE == 0) {
#pragma unroll
    for (int mt = 0; mt < MT; ++mt)
#pragma unroll
      for (int i = 0; i < 4; ++i) {
        const int row = bm * BM + wm + mt * 16 + quad * 4 + i;
#pragma unroll
        for (int nt = 0; nt < 4; ++nt) {
          const int col = bn * 128 + wn + nt * 16 + l16;
          C[row * N + col] = acc[mt][nt][i];
        }
      }
  } else {
    // per-wave LDS bounce buffer (reuses Bs; safe after final barrier above)
    bf16* tb = &Bs[wave * 512];  // 16 x 16 tile, stride 20 (conflict-free)
#pragma unroll
    for (int mt = 0; mt < MT; ++mt) {
      const int s0 = bm * BM + wm + mt * 16;  // = b*2048 + sbase, 16-aligned
      const int b = s0 >> 11, sbase = s0 & 2047;
#pragma unroll
      for (int nt = 0; nt < 4; ++nt) {
        const int colb = bn * 128 + wn + nt * 16;
        const int sec = colb >> 10, rem = colb & 1023;
        const int h = rem >> 6, d0 = rem & 63;
        if (sec < 2) {  // q or k: RoPE, bounce through LDS for b64 stores
          const int d = d0 + l16;
#pragma unroll
          for (int i = 0; i < 4; ++i) {
            const int s = sbase + quad * 4 + i;
            float v = acc[mt][nt][i];
            float pr = __shfl_xor(v, 1);  // partner dim d^1 (lane l16^1)
            float rot = (d & 1) ? pr : -pr;
            float rv = v * ropeC[s * 64 + d] + rot * ropeS[s * 64 + d];
            if (sec == 0) rv *= QSC;  // fold softmax scale*log2e into q
            tb[(quad * 4 + i) * 20 + l16] = (bf16)rv;
          }
          bf16* dst = ((sec == 0) ? qws : kws) + ((b * 16 + h) * 2048 + sbase) * 64 + d0;
          bf16x4 seg = *(const bf16x4*)&tb[l16 * 20 + quad * 4];
          *(bf16x4*)(dst + l16 * 64 + quad * 4) = seg;
        } else {  // v: store b64 to vT (d-major) at pi-permuted s position
          const int d = d0 + l16;
          const int s4 = sbase + quad * 4;
          const int a = (s4 >> 4) & 3;
          const int p = (s4 & ~63) | ((a >> 1) * 32 + quad * 8 + (a & 1) * 4);
          bf16x4 pk;
#pragma unroll
          for (int i = 0; i < 4; ++i) pk[i] = (bf16)acc[mt][nt][i];
          *(bf16x4*)(vT + ((b * 16 + h) * 64 + d) * 2048 + p) = pk;
        }
      }
    }
  }
}

// ---------------- dual-triangle attention v8: r10 structure + VALU trim ----
// r10's dbuf + explicit vmcnt drain kept identical. Changes: raw v_exp_f32
// via builtin; row-sum l accumulated by an extra MFMA against an all-ones
// B-frag (layout-invariant: D[m][n]=sum_k A[m][k]) -> lane-local v_rcp, no
// scalar adds, no end-of-kernel shuffles.
__global__ __launch_bounds__(256) void attn_k(const bf16* __restrict__ qws,
                                              const bf16* __restrict__ kws,
                                              const bf16* __restrict__ vT,
                                              bf16* __restrict__ aw) {
  __shared__ __align__(16) bf16 Ks[2][64 * 64];
  __shared__ __align__(16) bf16 Vs[2][64 * 64];
  const int tid = threadIdx.x;
  const int lane = tid & 63, wave = tid >> 6;
  const int l16 = lane & 15, quad = lane >> 4;
  const int bh = blockIdx.x >> 4, qblk = blockIdx.x & 15;
  const int b = bh >> 4, h = bh & 15;
  const int rbase = qblk * 128 + wave * 32;

  const bf16* qb = qws + (bh * 2048 + rbase) * 64;
  const bf16* kb = kws + bh * 2048 * 64;
  const bf16* vb = vT + bh * 64 * 2048;

  // staging: wave stages rows [wave*16, +16) of both tiles; 2 insts each.
  const int r0 = wave * 16 + (lane >> 3);
  const int c0 = ((lane & 7) - r0) & 7;  // chunk rotation (r0 and r0+8 give same c)
  const bf16* kst0 = kb + r0 * 64 + c0 * 8;
  const bf16* kst1 = kb + (r0 + 8) * 64 + c0 * 8;
  const bf16* vst0 = vb + r0 * 2048 + c0 * 8;
  const bf16* vst1 = vb + (r0 + 8) * 2048 + c0 * 8;

#define STAGE(jtv)                                         \
  {                                                        \
    bf16* kdst = &Ks[(jtv) & 1][wave * 1024];              \
    bf16* vdst = &Vs[(jtv) & 1][wave * 1024];              \
    async_cp16(kst0 + (jtv) * 4096, kdst);                 \
    async_cp16(kst1 + (jtv) * 4096, kdst + 512);           \
    async_cp16(vst0 + (jtv) * 64, vdst);                   \
    async_cp16(vst1 + (jtv) * 64, vdst + 512);             \
  }

  bf16x8 qf[2][2];
#pragma unroll
  for (int g = 0; g < 2; ++g)
#pragma unroll
    for (int hf = 0; hf < 2; ++hf)
      qf[g][hf] = *(const bf16x8*)(qb + (g * 16 + l16) * 64 + hf * 32 + quad * 8);

  bf16x8 ones;
#pragma unroll
  for (int j = 0; j < 8; ++j) ones[j] = (bf16)1.0f;

  f32x4 o[2][4] = {};
  f32x4 o_l[2] = {};
  const f32x4 zz = {};
  const int tdw = rbase >> 6;  // jt<tdw pure-down, ==tdw mixed, >tdw pure-up

#define ATTN_BODY(TM, jt)                                                             \
  {                                                                                   \
    const bf16* Kb = Ks[(jt) & 1];                                                    \
    const bf16* Vb = Vs[(jt) & 1];                                                    \
    bf16x8 vf[2][4];                                                                  \
    _Pragma("unroll") for (int ks = 0; ks < 2; ++ks)                                  \
      _Pragma("unroll") for (int ntd = 0; ntd < 4; ++ntd)                             \
        vf[ks][ntd] = *(const bf16x8*)(Vb + (ntd * 16 + l16) * 64 +                   \
                                       ((ks * 4 + quad + l16) & 7) * 8);              \
    bf16x8 kfU[2][2], kfD[2][2];                                                      \
    _Pragma("unroll") for (int ks = 0; ks < 2; ++ks)                                  \
      _Pragma("unroll") for (int s = 0; s < 2; ++s) {                                 \
        const int ro = ((ks * 2 + s) * 16 + l16) * 64;                                \
        if (TM != 0) kfU[ks][s] = *(const bf16x8*)(Kb + ro + ((quad + l16) & 7) * 8); \
        if (TM != 2)                                                                  \
          kfD[ks][s] = *(const bf16x8*)(Kb + ro + ((4 + quad + l16) & 7) * 8);        \
      }                                                                               \
    if ((jt) + 1 < 32) STAGE((jt) + 1)                                                \
    _Pragma("unroll") for (int ks = 0; ks < 2; ++ks) {                                \
      f32x4 sU[2][2], sD[2][2];                                                       \
      _Pragma("unroll") for (int s = 0; s < 2; ++s)                                   \
        _Pragma("unroll") for (int g = 0; g < 2; ++g) {                               \
          if (TM != 0) sU[s][g] = MFMA16(kfU[ks][s], qf[g][0], zz);                   \
          if (TM != 2) sD[s][g] = MFMA16(kfD[ks][s], qf[g][1], zz);                   \
        }                                                                             \
      _Pragma("unroll") for (int g = 0; g < 2; ++g) {                                 \
        bf16x8 af;                                                                    \
        _Pragma("unroll") for (int s = 0; s < 2; ++s)                                 \
          _Pragma("unroll") for (int r = 0; r < 4; ++r) {                             \
            float x;                                                                  \
            if (TM == 0) x = sD[s][g][r];                                             \
            else if (TM == 2) x = sU[s][g][r];                                        \
            else {                                                                    \
              const int jcol = (jt) * 64 + (ks * 2 + s) * 16 + quad * 4 + r;          \
              x = (jcol <= rbase + g * 16 + l16) ? sD[s][g][r] : sU[s][g][r];         \
            }                                                                         \
            af[s * 4 + r] = (bf16)__builtin_amdgcn_exp2f(x);                          \
          }                                                                           \
        o_l[g] = MFMA16(af, ones, o_l[g]);                                            \
        _Pragma("unroll") for (int ntd = 0; ntd < 4; ++ntd)                           \
            o[g][ntd] = MFMA16(af, vf[ks][ntd], o[g][ntd]);                           \
      }                                                                               \
    }                                                                                 \
  }

  STAGE(0)
  for (int jt = 0; jt < 32; ++jt) {
    // Force each wave's pending LDS-DMA retired before the barrier: guarantees
    // cross-wave visibility of STAGE(jt) (issued one iteration ago -> free).
    asm volatile("s_waitcnt vmcnt(0)" ::: "memory");
    __syncthreads();
    if (jt < tdw) ATTN_BODY(0, jt)
    else if (jt == tdw) ATTN_BODY(1, jt)
    else ATTN_BODY(2, jt)
  }
#undef ATTN_BODY
#undef STAGE

  // o_l lane layout == o lane layout (row = quad*4+r): lane-local normalize.
#pragma unroll
  for (int g = 0; g < 2; ++g) {
    float ir[4];
#pragma unroll
    for (int r = 0; r < 4; ++r) ir[r] = __builtin_amdgcn_rcpf(o_l[g][r]);
#pragma unroll
    for (int ntd = 0; ntd < 4; ++ntd)
#pragma unroll
      for (int r = 0; r < 4; ++r)
        aw[(b * 2048 + rbase + g * 16 + quad * 4 + r) * 1024 + h * 64 + ntd * 16 + l16] =
            (bf16)(o[g][ntd][r] * ir[r]);
  }
}

extern "C" void kernel_launch(void* const* d_in, const int* in_sizes, int n_in,
                              void* d_out, int out_size, void* d_ws, size_t ws_size,
                              hipStream_t stream) {
  const float* x = (const float*)d_in[0];       // (2,2048,1024) fp32
  const float* w_qkv = (const float*)d_in[1];   // (1024,3072) fp32
  const float* w_proj = (const float*)d_in[2];  // (1024,1024) fp32
  const float* ropeC = (const float*)d_in[3];   // (2048,64) fp32
  const float* ropeS = (const float*)d_in[4];   // (2048,64) fp32
  float* out = (float*)d_out;                   // (2,2048,1024) fp32

  char* ws = (char*)d_ws;
  bf16* xb = (bf16*)ws;     ws += (size_t)4194304 * 2;  // (4096,1024) bf16
  bf16* wqkvT = (bf16*)ws;  ws += (size_t)3145728 * 2;  // (3072,1024) N-major bf16
  bf16* wprojT = (bf16*)ws; ws += (size_t)1048576 * 2;  // (1024,1024) N-major bf16
  bf16* qws = (bf16*)ws;    ws += (size_t)4194304 * 2;  // (2,16,2048,64), q pre-scaled
  bf16* kws = (bf16*)ws;    ws += (size_t)4194304 * 2;  // (2,16,2048,64)
  bf16* vT = (bf16*)ws;     ws += (size_t)4194304 * 2;  // (2,16,64,2048), pi-permuted
  bf16* aw = (bf16*)ws;     ws += (size_t)4194304 * 2;  // (4096,1024)

  convx_k<<<1024, 256, 0, stream>>>(x, xb, 4194304);
  transpose_k<<<dim3(3072 / 64, 1024 / 64), 256, 0, stream>>>(w_qkv, wqkvT, 1024, 3072);
  transpose_k<<<dim3(1024 / 64, 1024 / 64), 256, 0, stream>>>(w_proj, wprojT, 1024, 1024);

  gemm128<1, 128><<<dim3(3072 / 128, 4096 / 128), 256, 0, stream>>>(
      xb, wqkvT, 4096, 3072, 1024, nullptr, qws, kws, vT, ropeC, ropeS);
  attn_k<<<512, 256, 0, stream>>>(qws, kws, vT, aw);
  gemm128<0, 64><<<dim3(1024 / 128, 4096 / 64), 256, 0, stream>>>(
      aw, wprojT, 4096, 1024, 1024, out, nullptr, nullptr, nullptr, nullptr, nullptr);
}

// Round 12
// 195.197 us; speedup vs baseline: 2.2492x; 1.0041x over previous
//
#include <hip/hip_runtime.h>
#include <hip/hip_bf16.h>
#include <stdint.h>

typedef __bf16 bf16;
typedef __attribute__((ext_vector_type(4))) __bf16 bf16x4;
typedef __attribute__((ext_vector_type(8))) __bf16 bf16x8;
typedef __attribute__((ext_vector_type(4))) float f32x4;

#define MFMA16(a, b, c) __builtin_amdgcn_mfma_f32_16x16x32_bf16((a), (b), (c), 0, 0, 0)

// scale (1/sqrt(32)) * log2(e), folded into q at the gemm1 epilogue
#define QSC (0.17677669529663687f * 1.4426950408889634f)

__device__ __forceinline__ void async_cp16(const bf16* g, bf16* l) {
  __builtin_amdgcn_global_load_lds(
      (const __attribute__((address_space(1))) void*)g,
      (__attribute__((address_space(3))) void*)l, 16, 0, 0);
}

// ---------- fused prep: x cast (blocks 0..1023) | w_qkv^T (1024..1791) |
// ---------- w_proj^T (1792..2047). Transposes: fp32 (R x C) -> bf16 (C x R).
__global__ __launch_bounds__(256) void prep_k(const float* __restrict__ x,
                                              bf16* __restrict__ xb,
                                              const float* __restrict__ wqkv,
                                              bf16* __restrict__ wqkvT,
                                              const float* __restrict__ wproj,
                                              bf16* __restrict__ wprojT) {
  __shared__ bf16 t[64][65];
  const int bid = blockIdx.x;
  if (bid < 1024) {  // x cast, 4 elems/thread grid-stride
    int i = (bid * 256 + threadIdx.x) * 4;
    const int stride = 1024 * 256 * 4;
    for (; i < 4194304; i += stride) {
      const f32x4 f = *(const f32x4*)(x + i);
      bf16x4 o;
      o[0] = (bf16)f[0]; o[1] = (bf16)f[1]; o[2] = (bf16)f[2]; o[3] = (bf16)f[3];
      *(bf16x4*)(xb + i) = o;
    }
    return;
  }
  const float* in;
  bf16* out;
  int R, C, tb;
  if (bid < 1792) { in = wqkv; out = wqkvT; R = 1024; C = 3072; tb = bid - 1024; }
  else            { in = wproj; out = wprojT; R = 1024; C = 1024; tb = bid - 1792; }
  const int tilesx = C >> 6;
  const int bc = (tb % tilesx) * 64, br = (tb / tilesx) * 64;
  const int tx = threadIdx.x & 63, ty = threadIdx.x >> 6;
#pragma unroll
  for (int r = ty; r < 64; r += 4) t[r][tx] = (bf16)in[(br + r) * C + bc + tx];
  __syncthreads();
#pragma unroll
  for (int r = ty; r < 64; r += 4) out[(bc + r) * R + br + tx] = t[tx][r];
}

// ---------------- BMx128 bf16 GEMM, BK=64, BT is N-major (N x K) ----------------
// LDS rows are chunk-rotated: 16B chunk c of row r sits at position (c+r)&7
// (keeps global_load_lds staging contiguous, makes b128 frag reads ~2-way only).
// MODE 0: fp32 store to C. MODE 1: qkv epilogue with RoPE + scatter (bf16);
// vT gets the attention pi-permutation on s within each 64-block (r8 comment).
template <int MODE, int BM>
__global__ __launch_bounds__(256) void gemm128(
    const bf16* __restrict__ A, const bf16* __restrict__ BT, int M, int N, int K,
    float* __restrict__ C, bf16* __restrict__ qws, bf16* __restrict__ kws,
    bf16* __restrict__ vT, const float* __restrict__ ropeC, const float* __restrict__ ropeS) {
  constexpr int MT = BM / 32;  // 16-row tiles per wave
  __shared__ __align__(16) bf16 As[BM * 64];
  __shared__ __align__(16) bf16 Bs[128 * 64];
  const int tid = threadIdx.x;
  const int lane = tid & 63, wave = tid >> 6;
  const int l16 = lane & 15, quad = lane >> 4;
  const int wm = (wave >> 1) * (BM / 2), wn = (wave & 1) * 64;
  const int bm = blockIdx.y, bn = blockIdx.x;

  // staging: thread t owns LDS row (t>>3) (+32 per inst), position t&7;
  // fetches global chunk ((t&7) - row) & 7 -> chunk g lands at pos (g+row)&7.
  const int srow = tid >> 3;
  const int schunk = ((tid & 7) - srow) & 7;
  const bf16* ag = A + (bm * BM + srow) * K + schunk * 8;
  const bf16* bg = BT + (bn * 128 + srow) * K + schunk * 8;
  bf16* la = &As[tid * 8];
  bf16* lb = &Bs[tid * 8];

  f32x4 acc[MT][4] = {};

  for (int k0 = 0; k0 < K; k0 += 64) {
    async_cp16(ag + k0, la);
    async_cp16(ag + 32 * K + k0, la + 2048);
    if (BM == 128) {
      async_cp16(ag + 64 * K + k0, la + 4096);
      async_cp16(ag + 96 * K + k0, la + 6144);
    }
    async_cp16(bg + k0, lb);
    async_cp16(bg + 32 * K + k0, lb + 2048);
    async_cp16(bg + 64 * K + k0, lb + 4096);
    async_cp16(bg + 96 * K + k0, lb + 6144);
    __syncthreads();
#pragma unroll
    for (int ks = 0; ks < 2; ++ks) {
      bf16x8 af[MT], bff[4];
#pragma unroll
      for (int t = 0; t < MT; ++t) {
        const int r = wm + t * 16 + l16;
        af[t] = *(const bf16x8*)&As[r * 64 + ((ks * 4 + quad + r) & 7) * 8];
      }
#pragma unroll
      for (int t = 0; t < 4; ++t) {
        const int r = wn + t * 16 + l16;
        bff[t] = *(const bf16x8*)&Bs[r * 64 + ((ks * 4 + quad + r) & 7) * 8];
      }
#pragma unroll
      for (int mt = 0; mt < MT; ++mt)
#pragma unroll
        for (int nt = 0; nt < 4; ++nt) acc[mt][nt] = MFMA16(af[mt], bff[nt], acc[mt][nt]);
    }
    __syncthreads();
  }

  if (MODE == 0) {
#pragma unroll
    for (int mt = 0; mt < MT; ++mt)
#pragma unroll
      for (int i = 0; i < 4; ++i) {
        const int row = bm * BM + wm + mt * 16 + quad * 4 + i;
#pragma unroll
        for (int nt = 0; nt < 4; ++nt) {
          const int col = bn * 128 + wn + nt * 16 + l16;
          C[row * N + col] = acc[mt][nt][i];
        }
      }
  } else {
    // per-wave LDS bounce buffer (reuses Bs; safe after final barrier above)
    bf16* tb = &Bs[wave * 512];  // 16 x 16 tile, stride 20 (conflict-free)
#pragma unroll
    for (int mt = 0; mt < MT; ++mt) {
      const int s0 = bm * BM + wm + mt * 16;  // = b*2048 + sbase, 16-aligned
      const int b = s0 >> 11, sbase = s0 & 2047;
#pragma unroll
      for (int nt = 0; nt < 4; ++nt) {
        const int colb = bn * 128 + wn + nt * 16;
        const int sec = colb >> 10, rem = colb & 1023;
        const int h = rem >> 6, d0 = rem & 63;
        if (sec < 2) {  // q or k: RoPE, bounce through LDS for b64 stores
          const int d = d0 + l16;
#pragma unroll
          for (int i = 0; i < 4; ++i) {
            const int s = sbase + quad * 4 + i;
            float v = acc[mt][nt][i];
            float pr = __shfl_xor(v, 1);  // partner dim d^1 (lane l16^1)
            float rot = (d & 1) ? pr : -pr;
            float rv = v * ropeC[s * 64 + d] + rot * ropeS[s * 64 + d];
            if (sec == 0) rv *= QSC;  // fold softmax scale*log2e into q
            tb[(quad * 4 + i) * 20 + l16] = (bf16)rv;
          }
          bf16* dst = ((sec == 0) ? qws : kws) + ((b * 16 + h) * 2048 + sbase) * 64 + d0;
          bf16x4 seg = *(const bf16x4*)&tb[l16 * 20 + quad * 4];
          *(bf16x4*)(dst + l16 * 64 + quad * 4) = seg;
        } else {  // v: store b64 to vT (d-major) at pi-permuted s position
          const int d = d0 + l16;
          const int s4 = sbase + quad * 4;
          const int a = (s4 >> 4) & 3;
          const int p = (s4 & ~63) | ((a >> 1) * 32 + quad * 8 + (a & 1) * 4);
          bf16x4 pk;
#pragma unroll
          for (int i = 0; i < 4; ++i) pk[i] = (bf16)acc[mt][nt][i];
          *(bf16x4*)(vT + ((b * 16 + h) * 64 + d) * 2048 + p) = pk;
        }
      }
    }
  }
}

// ---------------- dual-triangle attention v9: 64-row blocks for occupancy ----
// grid: 1024 blocks = 32 (b,h) * 32 Q-blocks(64 rows); wave owns 16 rows.
// Same verified v8 body (dbuf K/V + explicit vmcnt drain + ones-MFMA l), with
// the g-loop removed (1 row-group/wave) -> half the VGPRs, 4 blocks/CU target.
// tdw = qblk is wave-uniform.
__global__ __launch_bounds__(256) void attn_k(const bf16* __restrict__ qws,
                                              const bf16* __restrict__ kws,
                                              const bf16* __restrict__ vT,
                                              bf16* __restrict__ aw) {
  __shared__ __align__(16) bf16 Ks[2][64 * 64];
  __shared__ __align__(16) bf16 Vs[2][64 * 64];
  const int tid = threadIdx.x;
  const int lane = tid & 63, wave = tid >> 6;
  const int l16 = lane & 15, quad = lane >> 4;
  const int bh = blockIdx.x >> 5, qblk = blockIdx.x & 31;
  const int b = bh >> 4, h = bh & 15;
  const int rbase = qblk * 64 + wave * 16;

  const bf16* qb = qws + (bh * 2048 + rbase) * 64;
  const bf16* kb = kws + bh * 2048 * 64;
  const bf16* vb = vT + bh * 64 * 2048;

  // staging: wave stages rows [wave*16, +16) of both tiles; 2 insts each.
  const int r0 = wave * 16 + (lane >> 3);
  const int c0 = ((lane & 7) - r0) & 7;  // chunk rotation (r0 and r0+8 give same c)
  const bf16* kst0 = kb + r0 * 64 + c0 * 8;
  const bf16* kst1 = kb + (r0 + 8) * 64 + c0 * 8;
  const bf16* vst0 = vb + r0 * 2048 + c0 * 8;
  const bf16* vst1 = vb + (r0 + 8) * 2048 + c0 * 8;

#define STAGE(jtv)                                         \
  {                                                        \
    bf16* kdst = &Ks[(jtv) & 1][wave * 1024];              \
    bf16* vdst = &Vs[(jtv) & 1][wave * 1024];              \
    async_cp16(kst0 + (jtv) * 4096, kdst);                 \
    async_cp16(kst1 + (jtv) * 4096, kdst + 512);           \
    async_cp16(vst0 + (jtv) * 64, vdst);                   \
    async_cp16(vst1 + (jtv) * 64, vdst + 512);             \
  }

  bf16x8 qf[2];
#pragma unroll
  for (int hf = 0; hf < 2; ++hf)
    qf[hf] = *(const bf16x8*)(qb + l16 * 64 + hf * 32 + quad * 8);

  bf16x8 ones;
#pragma unroll
  for (int j = 0; j < 8; ++j) ones[j] = (bf16)1.0f;

  f32x4 o[4] = {};
  f32x4 o_l = {};
  const f32x4 zz = {};
  const int tdw = qblk;  // jt<tdw pure-down, ==tdw mixed, >tdw pure-up

#define ATTN_BODY(TM, jt)                                                             \
  {                                                                                   \
    const bf16* Kb = Ks[(jt) & 1];                                                    \
    const bf16* Vb = Vs[(jt) & 1];                                                    \
    bf16x8 vf[2][4];                                                                  \
    _Pragma("unroll") for (int ks = 0; ks < 2; ++ks)                                  \
      _Pragma("unroll") for (int ntd = 0; ntd < 4; ++ntd)                             \
        vf[ks][ntd] = *(const bf16x8*)(Vb + (ntd * 16 + l16) * 64 +                   \
                                       ((ks * 4 + quad + l16) & 7) * 8);              \
    bf16x8 kfU[2][2], kfD[2][2];                                                      \
    _Pragma("unroll") for (int ks = 0; ks < 2; ++ks)                                  \
      _Pragma("unroll") for (int s = 0; s < 2; ++s) {                                 \
        const int ro = ((ks * 2 + s) * 16 + l16) * 64;                                \
        if (TM != 0) kfU[ks][s] = *(const bf16x8*)(Kb + ro + ((quad + l16) & 7) * 8); \
        if (TM != 2)                                                                  \
          kfD[ks][s] = *(const bf16x8*)(Kb + ro + ((4 + quad + l16) & 7) * 8);        \
      }                                                                               \
    if ((jt) + 1 < 32) STAGE((jt) + 1)                                                \
    _Pragma("unroll") for (int ks = 0; ks < 2; ++ks) {                                \
      f32x4 sU[2], sD[2];                                                             \
      _Pragma("unroll") for (int s = 0; s < 2; ++s) {                                 \
        if (TM != 0) sU[s] = MFMA16(kfU[ks][s], qf[0], zz);                           \
        if (TM != 2) sD[s] = MFMA16(kfD[ks][s], qf[1], zz);                           \
      }                                                                               \
      bf16x8 af;                                                                      \
      _Pragma("unroll") for (int s = 0; s < 2; ++s)                                   \
        _Pragma("unroll") for (int r = 0; r < 4; ++r) {                               \
          float x;                                                                    \
          if (TM == 0) x = sD[s][r];                                                  \
          else if (TM == 2) x = sU[s][r];                                             \
          else {                                                                      \
            const int jcol = (jt) * 64 + (ks * 2 + s) * 16 + quad * 4 + r;            \
            x = (jcol <= rbase + l16) ? sD[s][r] : sU[s][r];                          \
          }                                                                           \
          af[s * 4 + r] = (bf16)__builtin_amdgcn_exp2f(x);                            \
        }                                                                             \
      o_l = MFMA16(af, ones, o_l);                                                    \
      _Pragma("unroll") for (int ntd = 0; ntd < 4; ++ntd)                             \
          o[ntd] = MFMA16(af, vf[ks][ntd], o[ntd]);                                   \
    }                                                                                 \
  }

  STAGE(0)
  for (int jt = 0; jt < 32; ++jt) {
    // Force each wave's pending LDS-DMA retired before the barrier: guarantees
    // cross-wave visibility of STAGE(jt) (issued one iteration ago -> free).
    asm volatile("s_waitcnt vmcnt(0)" ::: "memory");
    __syncthreads();
    if (jt < tdw) ATTN_BODY(0, jt)
    else if (jt == tdw) ATTN_BODY(1, jt)
    else ATTN_BODY(2, jt)
  }
#undef ATTN_BODY
#undef STAGE

  // o_l lane layout == o lane layout (row = quad*4+r): lane-local normalize.
  float ir[4];
#pragma unroll
  for (int r = 0; r < 4; ++r) ir[r] = __builtin_amdgcn_rcpf(o_l[r]);
#pragma unroll
  for (int ntd = 0; ntd < 4; ++ntd)
#pragma unroll
    for (int r = 0; r < 4; ++r)
      aw[(b * 2048 + rbase + quad * 4 + r) * 1024 + h * 64 + ntd * 16 + l16] =
          (bf16)(o[ntd][r] * ir[r]);
}

extern "C" void kernel_launch(void* const* d_in, const int* in_sizes, int n_in,
                              void* d_out, int out_size, void* d_ws, size_t ws_size,
                              hipStream_t stream) {
  const float* x = (const float*)d_in[0];       // (2,2048,1024) fp32
  const float* w_qkv = (const float*)d_in[1];   // (1024,3072) fp32
  const float* w_proj = (const float*)d_in[2];  // (1024,1024) fp32
  const float* ropeC = (const float*)d_in[3];   // (2048,64) fp32
  const float* ropeS = (const float*)d_in[4];   // (2048,64) fp32
  float* out = (float*)d_out;                   // (2,2048,1024) fp32

  char* ws = (char*)d_ws;
  bf16* xb = (bf16*)ws;     ws += (size_t)4194304 * 2;  // (4096,1024) bf16
  bf16* wqkvT = (bf16*)ws;  ws += (size_t)3145728 * 2;  // (3072,1024) N-major bf16
  bf16* wprojT = (bf16*)ws; ws += (size_t)1048576 * 2;  // (1024,1024) N-major bf16
  bf16* qws = (bf16*)ws;    ws += (size_t)4194304 * 2;  // (2,16,2048,64), q pre-scaled
  bf16* kws = (bf16*)ws;    ws += (size_t)4194304 * 2;  // (2,16,2048,64)
  bf16* vT = (bf16*)ws;     ws += (size_t)4194304 * 2;  // (2,16,64,2048), pi-permuted
  bf16* aw = (bf16*)ws;     ws += (size_t)4194304 * 2;  // (4096,1024)

  prep_k<<<2048, 256, 0, stream>>>(x, xb, w_qkv, wqkvT, w_proj, wprojT);
  gemm128<1, 128><<<dim3(3072 / 128, 4096 / 128), 256, 0, stream>>>(
      xb, wqkvT, 4096, 3072, 1024, nullptr, qws, kws, vT, ropeC, ropeS);
  attn_k<<<1024, 256, 0, stream>>>(qws, kws, vT, aw);
  gemm128<0, 64><<<dim3(1024 / 128, 4096 / 64), 256, 0, stream>>>(
      aw, wprojT, 4096, 1024, 1024, out, nullptr, nullptr, nullptr, nullptr, nullptr);
}

// Round 13
// 185.006 us; speedup vs baseline: 2.3731x; 1.0551x over previous
//
#include <hip/hip_runtime.h>
#include <hip/hip_bf16.h>
#include <stdint.h>

typedef __bf16 bf16;
typedef __attribute__((ext_vector_type(4))) __bf16 bf16x4;
typedef __attribute__((ext_vector_type(8))) __bf16 bf16x8;
typedef __attribute__((ext_vector_type(4))) float f32x4;

#define MFMA16(a, b, c) __builtin_amdgcn_mfma_f32_16x16x32_bf16((a), (b), (c), 0, 0, 0)

// scale (1/sqrt(32)) * log2(e), folded into q at the gemm1 epilogue
#define QSC (0.17677669529663687f * 1.4426950408889634f)

__device__ __forceinline__ void async_cp16(const bf16* g, bf16* l) {
  __builtin_amdgcn_global_load_lds(
      (const __attribute__((address_space(1))) void*)g,
      (__attribute__((address_space(3))) void*)l, 16, 0, 0);
}

// ---------- fused prep: x cast (blocks 0..1023) | w_qkv^T (1024..1791) |
// ---------- w_proj^T (1792..2047). Transposes: fp32 (R x C) -> bf16 (C x R).
__global__ __launch_bounds__(256) void prep_k(const float* __restrict__ x,
                                              bf16* __restrict__ xb,
                                              const float* __restrict__ wqkv,
                                              bf16* __restrict__ wqkvT,
                                              const float* __restrict__ wproj,
                                              bf16* __restrict__ wprojT) {
  __shared__ bf16 t[64][65];
  const int bid = blockIdx.x;
  if (bid < 1024) {  // x cast, 4 elems/thread grid-stride
    int i = (bid * 256 + threadIdx.x) * 4;
    const int stride = 1024 * 256 * 4;
    for (; i < 4194304; i += stride) {
      const f32x4 f = *(const f32x4*)(x + i);
      bf16x4 o;
      o[0] = (bf16)f[0]; o[1] = (bf16)f[1]; o[2] = (bf16)f[2]; o[3] = (bf16)f[3];
      *(bf16x4*)(xb + i) = o;
    }
    return;
  }
  const float* in;
  bf16* out;
  int R, C, tb;
  if (bid < 1792) { in = wqkv; out = wqkvT; R = 1024; C = 3072; tb = bid - 1024; }
  else            { in = wproj; out = wprojT; R = 1024; C = 1024; tb = bid - 1792; }
  const int tilesx = C >> 6;
  const int bc = (tb % tilesx) * 64, br = (tb / tilesx) * 64;
  const int tx = threadIdx.x & 63, ty = threadIdx.x >> 6;
#pragma unroll
  for (int r = ty; r < 64; r += 4) t[r][tx] = (bf16)in[(br + r) * C + bc + tx];
  __syncthreads();
#pragma unroll
  for (int r = ty; r < 64; r += 4) out[(bc + r) * R + br + tx] = t[tx][r];
}

// ---------------- BMx128 bf16 GEMM, BK=64, BT is N-major (N x K) ----------------
// LDS rows are chunk-rotated: 16B chunk c of row r sits at position (c+r)&7
// (keeps global_load_lds staging contiguous, makes b128 frag reads ~2-way only).
// MODE 0: fp32 store to C. MODE 1: qkv epilogue with RoPE + scatter (bf16);
// vT gets the attention pi-permutation on s within each 64-block (r8 comment).
template <int MODE, int BM>
__global__ __launch_bounds__(256) void gemm128(
    const bf16* __restrict__ A, const bf16* __restrict__ BT, int M, int N, int K,
    float* __restrict__ C, bf16* __restrict__ qws, bf16* __restrict__ kws,
    bf16* __restrict__ vT, const float* __restrict__ ropeC, const float* __restrict__ ropeS) {
  constexpr int MT = BM / 32;  // 16-row tiles per wave
  __shared__ __align__(16) bf16 As[BM * 64];
  __shared__ __align__(16) bf16 Bs[128 * 64];
  const int tid = threadIdx.x;
  const int lane = tid & 63, wave = tid >> 6;
  const int l16 = lane & 15, quad = lane >> 4;
  const int wm = (wave >> 1) * (BM / 2), wn = (wave & 1) * 64;
  const int bm = blockIdx.y, bn = blockIdx.x;

  // staging: thread t owns LDS row (t>>3) (+32 per inst), position t&7;
  // fetches global chunk ((t&7) - row) & 7 -> chunk g lands at pos (g+row)&7.
  const int srow = tid >> 3;
  const int schunk = ((tid & 7) - srow) & 7;
  const bf16* ag = A + (bm * BM + srow) * K + schunk * 8;
  const bf16* bg = BT + (bn * 128 + srow) * K + schunk * 8;
  bf16* la = &As[tid * 8];
  bf16* lb = &Bs[tid * 8];

  f32x4 acc[MT][4] = {};

  for (int k0 = 0; k0 < K; k0 += 64) {
    async_cp16(ag + k0, la);
    async_cp16(ag + 32 * K + k0, la + 2048);
    if (BM == 128) {
      async_cp16(ag + 64 * K + k0, la + 4096);
      async_cp16(ag + 96 * K + k0, la + 6144);
    }
    async_cp16(bg + k0, lb);
    async_cp16(bg + 32 * K + k0, lb + 2048);
    async_cp16(bg + 64 * K + k0, lb + 4096);
    async_cp16(bg + 96 * K + k0, lb + 6144);
    __syncthreads();
#pragma unroll
    for (int ks = 0; ks < 2; ++ks) {
      bf16x8 af[MT], bff[4];
#pragma unroll
      for (int t = 0; t < MT; ++t) {
        const int r = wm + t * 16 + l16;
        af[t] = *(const bf16x8*)&As[r * 64 + ((ks * 4 + quad + r) & 7) * 8];
      }
#pragma unroll
      for (int t = 0; t < 4; ++t) {
        const int r = wn + t * 16 + l16;
        bff[t] = *(const bf16x8*)&Bs[r * 64 + ((ks * 4 + quad + r) & 7) * 8];
      }
#pragma unroll
      for (int mt = 0; mt < MT; ++mt)
#pragma unroll
        for (int nt = 0; nt < 4; ++nt) acc[mt][nt] = MFMA16(af[mt], bff[nt], acc[mt][nt]);
    }
    __syncthreads();
  }

  if (MODE == 0) {
#pragma unroll
    for (int mt = 0; mt < MT; ++mt)
#pragma unroll
      for (int i = 0; i < 4; ++i) {
        const int row = bm * BM + wm + mt * 16 + quad * 4 + i;
#pragma unroll
        for (int nt = 0; nt < 4; ++nt) {
          const int col = bn * 128 + wn + nt * 16 + l16;
          C[row * N + col] = acc[mt][nt][i];
        }
      }
  } else {
    // per-wave LDS bounce buffer (reuses Bs; safe after final barrier above)
    bf16* tb = &Bs[wave * 512];  // 16 x 16 tile, stride 20 (conflict-free)
#pragma unroll
    for (int mt = 0; mt < MT; ++mt) {
      const int s0 = bm * BM + wm + mt * 16;  // = b*2048 + sbase, 16-aligned
      const int b = s0 >> 11, sbase = s0 & 2047;
#pragma unroll
      for (int nt = 0; nt < 4; ++nt) {
        const int colb = bn * 128 + wn + nt * 16;
        const int sec = colb >> 10, rem = colb & 1023;
        const int h = rem >> 6, d0 = rem & 63;
        if (sec < 2) {  // q or k: RoPE, bounce through LDS for b64 stores
          const int d = d0 + l16;
#pragma unroll
          for (int i = 0; i < 4; ++i) {
            const int s = sbase + quad * 4 + i;
            float v = acc[mt][nt][i];
            float pr = __shfl_xor(v, 1);  // partner dim d^1 (lane l16^1)
            float rot = (d & 1) ? pr : -pr;
            float rv = v * ropeC[s * 64 + d] + rot * ropeS[s * 64 + d];
            if (sec == 0) rv *= QSC;  // fold softmax scale*log2e into q
            tb[(quad * 4 + i) * 20 + l16] = (bf16)rv;
          }
          bf16* dst = ((sec == 0) ? qws : kws) + ((b * 16 + h) * 2048 + sbase) * 64 + d0;
          bf16x4 seg = *(const bf16x4*)&tb[l16 * 20 + quad * 4];
          *(bf16x4*)(dst + l16 * 64 + quad * 4) = seg;
        } else {  // v: store b64 to vT (d-major) at pi-permuted s position
          const int d = d0 + l16;
          const int s4 = sbase + quad * 4;
          const int a = (s4 >> 4) & 3;
          const int p = (s4 & ~63) | ((a >> 1) * 32 + quad * 8 + (a & 1) * 4);
          bf16x4 pk;
#pragma unroll
          for (int i = 0; i < 4; ++i) pk[i] = (bf16)acc[mt][nt][i];
          *(bf16x4*)(vT + ((b * 16 + h) * 64 + d) * 2048 + p) = pk;
        }
      }
    }
  }
}

// ---------------- dual-triangle attention v8 (r11-verified, reverted from v9) ----
// grid: 512 blocks = 32 (b,h) * 16 Q-blocks(128 rows); wave owns 32 rows.
// dbuf K/V + explicit vmcnt drain + ones-MFMA l. r12 taught: 64-row tiles halve
// per-wave MFMA at constant LDS-read cost -> keep 128-row / 32-rows-per-wave.
__global__ __launch_bounds__(256) void attn_k(const bf16* __restrict__ qws,
                                              const bf16* __restrict__ kws,
                                              const bf16* __restrict__ vT,
                                              bf16* __restrict__ aw) {
  __shared__ __align__(16) bf16 Ks[2][64 * 64];
  __shared__ __align__(16) bf16 Vs[2][64 * 64];
  const int tid = threadIdx.x;
  const int lane = tid & 63, wave = tid >> 6;
  const int l16 = lane & 15, quad = lane >> 4;
  const int bh = blockIdx.x >> 4, qblk = blockIdx.x & 15;
  const int b = bh >> 4, h = bh & 15;
  const int rbase = qblk * 128 + wave * 32;

  const bf16* qb = qws + (bh * 2048 + rbase) * 64;
  const bf16* kb = kws + bh * 2048 * 64;
  const bf16* vb = vT + bh * 64 * 2048;

  // staging: wave stages rows [wave*16, +16) of both tiles; 2 insts each.
  const int r0 = wave * 16 + (lane >> 3);
  const int c0 = ((lane & 7) - r0) & 7;  // chunk rotation (r0 and r0+8 give same c)
  const bf16* kst0 = kb + r0 * 64 + c0 * 8;
  const bf16* kst1 = kb + (r0 + 8) * 64 + c0 * 8;
  const bf16* vst0 = vb + r0 * 2048 + c0 * 8;
  const bf16* vst1 = vb + (r0 + 8) * 2048 + c0 * 8;

#define STAGE(jtv)                                         \
  {                                                        \
    bf16* kdst = &Ks[(jtv) & 1][wave * 1024];              \
    bf16* vdst = &Vs[(jtv) & 1][wave * 1024];              \
    async_cp16(kst0 + (jtv) * 4096, kdst);                 \
    async_cp16(kst1 + (jtv) * 4096, kdst + 512);           \
    async_cp16(vst0 + (jtv) * 64, vdst);                   \
    async_cp16(vst1 + (jtv) * 64, vdst + 512);             \
  }

  bf16x8 qf[2][2];
#pragma unroll
  for (int g = 0; g < 2; ++g)
#pragma unroll
    for (int hf = 0; hf < 2; ++hf)
      qf[g][hf] = *(const bf16x8*)(qb + (g * 16 + l16) * 64 + hf * 32 + quad * 8);

  bf16x8 ones;
#pragma unroll
  for (int j = 0; j < 8; ++j) ones[j] = (bf16)1.0f;

  f32x4 o[2][4] = {};
  f32x4 o_l[2] = {};
  const f32x4 zz = {};
  const int tdw = rbase >> 6;  // jt<tdw pure-down, ==tdw mixed, >tdw pure-up

#define ATTN_BODY(TM, jt)                                                             \
  {                                                                                   \
    const bf16* Kb = Ks[(jt) & 1];                                                    \
    const bf16* Vb = Vs[(jt) & 1];                                                    \
    bf16x8 vf[2][4];                                                                  \
    _Pragma("unroll") for (int ks = 0; ks < 2; ++ks)                                  \
      _Pragma("unroll") for (int ntd = 0; ntd < 4; ++ntd)                             \
        vf[ks][ntd] = *(const bf16x8*)(Vb + (ntd * 16 + l16) * 64 +                   \
                                       ((ks * 4 + quad + l16) & 7) * 8);              \
    bf16x8 kfU[2][2], kfD[2][2];                                                      \
    _Pragma("unroll") for (int ks = 0; ks < 2; ++ks)                                  \
      _Pragma("unroll") for (int s = 0; s < 2; ++s) {                                 \
        const int ro = ((ks * 2 + s) * 16 + l16) * 64;                                \
        if (TM != 0) kfU[ks][s] = *(const bf16x8*)(Kb + ro + ((quad + l16) & 7) * 8); \
        if (TM != 2)                                                                  \
          kfD[ks][s] = *(const bf16x8*)(Kb + ro + ((4 + quad + l16) & 7) * 8);        \
      }                                                                               \
    if ((jt) + 1 < 32) STAGE((jt) + 1)                                                \
    _Pragma("unroll") for (int ks = 0; ks < 2; ++ks) {                                \
      f32x4 sU[2][2], sD[2][2];                                                       \
      _Pragma("unroll") for (int s = 0; s < 2; ++s)                                   \
        _Pragma("unroll") for (int g = 0; g < 2; ++g) {                               \
          if (TM != 0) sU[s][g] = MFMA16(kfU[ks][s], qf[g][0], zz);                   \
          if (TM != 2) sD[s][g] = MFMA16(kfD[ks][s], qf[g][1], zz);                   \
        }                                                                             \
      _Pragma("unroll") for (int g = 0; g < 2; ++g) {                                 \
        bf16x8 af;                                                                    \
        _Pragma("unroll") for (int s = 0; s < 2; ++s)                                 \
          _Pragma("unroll") for (int r = 0; r < 4; ++r) {                             \
            float x;                                                                  \
            if (TM == 0) x = sD[s][g][r];                                             \
            else if (TM == 2) x = sU[s][g][r];                                        \
            else {                                                                    \
              const int jcol = (jt) * 64 + (ks * 2 + s) * 16 + quad * 4 + r;          \
              x = (jcol <= rbase + g * 16 + l16) ? sD[s][g][r] : sU[s][g][r];         \
            }                                                                         \
            af[s * 4 + r] = (bf16)__builtin_amdgcn_exp2f(x);                          \
          }                                                                           \
        o_l[g] = MFMA16(af, ones, o_l[g]);                                            \
        _Pragma("unroll") for (int ntd = 0; ntd < 4; ++ntd)                           \
            o[g][ntd] = MFMA16(af, vf[ks][ntd], o[g][ntd]);                           \
      }                                                                               \
    }                                                                                 \
  }

  STAGE(0)
  for (int jt = 0; jt < 32; ++jt) {
    // Force each wave's pending LDS-DMA retired before the barrier: guarantees
    // cross-wave visibility of STAGE(jt) (issued one iteration ago -> free).
    asm volatile("s_waitcnt vmcnt(0)" ::: "memory");
    __syncthreads();
    if (jt < tdw) ATTN_BODY(0, jt)
    else if (jt == tdw) ATTN_BODY(1, jt)
    else ATTN_BODY(2, jt)
  }
#undef ATTN_BODY
#undef STAGE

  // o_l lane layout == o lane layout (row = quad*4+r): lane-local normalize.
#pragma unroll
  for (int g = 0; g < 2; ++g) {
    float ir[4];
#pragma unroll
    for (int r = 0; r < 4; ++r) ir[r] = __builtin_amdgcn_rcpf(o_l[g][r]);
#pragma unroll
    for (int ntd = 0; ntd < 4; ++ntd)
#pragma unroll
      for (int r = 0; r < 4; ++r)
        aw[(b * 2048 + rbase + g * 16 + quad * 4 + r) * 1024 + h * 64 + ntd * 16 + l16] =
            (bf16)(o[g][ntd][r] * ir[r]);
  }
}

extern "C" void kernel_launch(void* const* d_in, const int* in_sizes, int n_in,
                              void* d_out, int out_size, void* d_ws, size_t ws_size,
                              hipStream_t stream) {
  const float* x = (const float*)d_in[0];       // (2,2048,1024) fp32
  const float* w_qkv = (const float*)d_in[1];   // (1024,3072) fp32
  const float* w_proj = (const float*)d_in[2];  // (1024,1024) fp32
  const float* ropeC = (const float*)d_in[3];   // (2048,64) fp32
  const float* ropeS = (const float*)d_in[4];   // (2048,64) fp32
  float* out = (float*)d_out;                   // (2,2048,1024) fp32

  char* ws = (char*)d_ws;
  bf16* xb = (bf16*)ws;     ws += (size_t)4194304 * 2;  // (4096,1024) bf16
  bf16* wqkvT = (bf16*)ws;  ws += (size_t)3145728 * 2;  // (3072,1024) N-major bf16
  bf16* wprojT = (bf16*)ws; ws += (size_t)1048576 * 2;  // (1024,1024) N-major bf16
  bf16* qws = (bf16*)ws;    ws += (size_t)4194304 * 2;  // (2,16,2048,64), q pre-scaled
  bf16* kws = (bf16*)ws;    ws += (size_t)4194304 * 2;  // (2,16,2048,64)
  bf16* vT = (bf16*)ws;     ws += (size_t)4194304 * 2;  // (2,16,64,2048), pi-permuted
  bf16* aw = (bf16*)ws;     ws += (size_t)4194304 * 2;  // (4096,1024)

  prep_k<<<2048, 256, 0, stream>>>(x, xb, w_qkv, wqkvT, w_proj, wprojT);
  gemm128<1, 128><<<dim3(3072 / 128, 4096 / 128), 256, 0, stream>>>(
      xb, wqkvT, 4096, 3072, 1024, nullptr, qws, kws, vT, ropeC, ropeS);
  attn_k<<<512, 256, 0, stream>>>(qws, kws, vT, aw);
  gemm128<0, 64><<<dim3(1024 / 128, 4096 / 64), 256, 0, stream>>>(
      aw, wprojT, 4096, 1024, 1024, out, nullptr, nullptr, nullptr, nullptr, nullptr);
}